// Round 2
// baseline (4244.331 us; speedup 1.0000x reference)
//
#include <hip/hip_runtime.h>
#include <math.h>

__device__ __forceinline__ float gelu_f(float x){
  return 0.5f * x * (1.0f + erff(x * 0.70710678118654752440f));
}

struct F8 { float v[8]; };
__device__ __forceinline__ F8 load8f(const float* p){
  float4 a = *(const float4*)p; float4 b = *(const float4*)(p + 4);
  F8 r; r.v[0]=a.x; r.v[1]=a.y; r.v[2]=a.z; r.v[3]=a.w;
  r.v[4]=b.x; r.v[5]=b.y; r.v[6]=b.z; r.v[7]=b.w; return r;
}

// PRE layout per batch (stride 4624 floats):
//   [0..2047]    wdiff[h][i]  (h*512+i)
//   [2048..2051] beta[h]
//   [2064..2575] base[r]
//   [2576..4623] M[r][h]      (r*4+h)
#define PRE_STRIDE 4624

// ---------------- K0: group-token MLPs -> k,v -> rank-4 attn precompute ----
__global__ __launch_bounds__(256) void k0_pre(
    const float* __restrict__ gtok,
    const float* __restrict__ ws1_w, const float* __restrict__ ws1_b,
    const float* __restrict__ ws2_w, const float* __restrict__ ws2_b,
    const float* __restrict__ wc1_w, const float* __restrict__ wc1_b,
    const float* __restrict__ wc2_w, const float* __restrict__ wc2_b,
    const float* __restrict__ q_w, const float* __restrict__ q_b,
    const float* __restrict__ k_w,
    const float* __restrict__ v_w, const float* __restrict__ v_b,
    const float* __restrict__ merge_w, const float* __restrict__ merge_b,
    float* __restrict__ PRE)
{
  __shared__ float gt[512][2];
  __shared__ float hid[2048];
  __shared__ float sw1[256][2]; __shared__ float sb1[256];
  __shared__ float sw2[2][256];
  __shared__ float dk[512], dv[512], v1l[512];
  const int b = blockIdx.x;
  const int t = threadIdx.x;
  sw1[t][0] = ws1_w[2*t]; sw1[t][1] = ws1_w[2*t+1];
  sb1[t] = ws1_b[t];
  sw2[0][t] = ws2_w[t]; sw2[1][t] = ws2_w[256+t];
  for (int d = t; d < 512; d += 256){
    gt[d][0] = gtok[b*1024 + 2*d]; gt[d][1] = gtok[b*1024 + 2*d + 1];
  }
  __syncthreads();
  const float s2b0 = ws2_b[0], s2b1 = ws2_b[1];
  // mlp_s over D positions (2 -> 256 -> 2), residual into gt
  for (int j = t; j < 512; j += 256){
    float a0 = gt[j][0], a1 = gt[j][1];
    float s0 = s2b0, s1 = s2b1;
    #pragma unroll 4
    for (int o = 0; o < 256; ++o){
      float h = gelu_f(sw1[o][0]*a0 + sw1[o][1]*a1 + sb1[o]);
      s0 += sw2[0][o]*h; s1 += sw2[1][o]*h;
    }
    gt[j][0] = a0 + s0; gt[j][1] = a1 + s1;
  }
  __syncthreads();
  // mlp_c (D -> 4D -> D) per token, residual into gt
  for (int tt = 0; tt < 2; ++tt){
    for (int o = t; o < 2048; o += 256){
      const float* wr = wc1_w + (size_t)o*512;
      float acc = wc1_b[o];
      for (int d = 0; d < 512; d += 8){
        F8 w = load8f(wr + d);
        #pragma unroll
        for (int i = 0; i < 8; ++i) acc += w.v[i]*gt[d+i][tt];
      }
      hid[o] = gelu_f(acc);
    }
    __syncthreads();
    for (int d = t; d < 512; d += 256){
      const float* wr = wc2_w + (size_t)d*2048;
      float acc = wc2_b[d];
      for (int o = 0; o < 2048; o += 8){
        F8 w = load8f(wr + o);
        #pragma unroll
        for (int i = 0; i < 8; ++i) acc += w.v[i]*hid[o+i];
      }
      gt[d][tt] += acc;
    }
    __syncthreads();
  }
  // k,v for both tokens; keep dk=k0-k1 (k bias cancels), dv=v0-v1, v1+vb
  for (int c = t; c < 512; c += 256){
    const float* kr = k_w + (size_t)c*512;
    const float* vr = v_w + (size_t)c*512;
    float k0a=0.f,k1a=0.f,v0a=0.f,v1a=0.f;
    for (int d = 0; d < 512; d += 8){
      F8 kw = load8f(kr + d); F8 vw = load8f(vr + d);
      #pragma unroll
      for (int i = 0; i < 8; ++i){
        float g0 = gt[d+i][0], g1 = gt[d+i][1];
        k0a += kw.v[i]*g0; k1a += kw.v[i]*g1;
        v0a += vw.v[i]*g0; v1a += vw.v[i]*g1;
      }
    }
    dk[c] = k0a - k1a; dv[c] = v0a - v1a; v1l[c] = v1a + v_b[c];
  }
  __syncthreads();
  float* P = PRE + (size_t)b * PRE_STRIDE;
  // wdiff[h][i] = sum_{c in head h} dk[c] * q_w[c][i]
  for (int i = t; i < 512; i += 256){
    float w0=0.f,w1=0.f,w2=0.f,w3=0.f;
    for (int c = 0; c < 512; c += 4){
      w0 += dk[c]  *q_w[(size_t)(c)  *512 + i];
      w1 += dk[c+1]*q_w[(size_t)(c+1)*512 + i];
      w2 += dk[c+2]*q_w[(size_t)(c+2)*512 + i];
      w3 += dk[c+3]*q_w[(size_t)(c+3)*512 + i];
    }
    P[0*512+i]=w0; P[1*512+i]=w1; P[2*512+i]=w2; P[3*512+i]=w3;
  }
  if (t < 4){
    float bsum = 0.f;
    for (int c = t; c < 512; c += 4) bsum += dk[c]*q_b[c];
    P[2048 + t] = bsum;
  }
  // base[r] = merge_b[r] + merge_w[r,:].v1 ; M[r][h] = sum_{c in h} mw[r,c]*dv[c]
  for (int r = t; r < 512; r += 256){
    const float* mw = merge_w + (size_t)r*512;
    float ab = merge_b[r];
    float m0=0.f,m1=0.f,m2=0.f,m3=0.f;
    for (int c = 0; c < 512; c += 4){
      float a0=mw[c],a1=mw[c+1],a2=mw[c+2],a3=mw[c+3];
      ab += a0*v1l[c]+a1*v1l[c+1]+a2*v1l[c+2]+a3*v1l[c+3];
      m0 += a0*dv[c]; m1 += a1*dv[c+1]; m2 += a2*dv[c+2]; m3 += a3*dv[c+3];
    }
    P[2064 + r] = ab;
    float4 mv = make_float4(m0,m1,m2,m3);
    *(float4*)&P[2576 + r*4] = mv;
  }
}

// ---------------- K1: fused q-dot + sigmoid attn + merge + LN(n0) ----------
__global__ __launch_bounds__(256) void k1_amln(
    const float* __restrict__ x, const float* __restrict__ PRE,
    const float* __restrict__ n0_g, const float* __restrict__ n0_b,
    int j0_global, int cstride, float* __restrict__ OutY)
{
  __shared__ float wd[4][512];
  __shared__ float bs[512];
  __shared__ float Mm[512][4];
  __shared__ float gam[512], bet[512];
  __shared__ float beta4[4];
  const int tid = threadIdx.x;
  const int jl = blockIdx.x*256 + tid;
  const int jg = j0_global + jl;
  const int b = jg >> 12, n = jg & 4095;
  const float* P = PRE + (size_t)b * PRE_STRIDE;
  for (int i = tid; i < 2048; i += 256) wd[i>>9][i&511] = P[i];
  if (tid < 4) beta4[tid] = P[2048 + tid];
  for (int i = tid; i < 512; i += 256){
    bs[i] = P[2064 + i]; gam[i] = n0_g[i]; bet[i] = n0_b[i];
  }
  for (int i = tid; i < 2048; i += 256) Mm[i>>2][i&3] = P[2576 + i];
  __syncthreads();
  const float* xc = x + (size_t)b*2097152 + n;
  float l0=beta4[0], l1=beta4[1], l2=beta4[2], l3=beta4[3];
  for (int i = 0; i < 512; ++i){
    float xv = xc[(size_t)i*4096];
    l0 += wd[0][i]*xv; l1 += wd[1][i]*xv; l2 += wd[2][i]*xv; l3 += wd[3][i]*xv;
  }
  const float sc = 0.0883883476483184405f;  // 1/sqrt(128)
  float p0 = 1.f/(1.f+expf(-sc*l0));
  float p1 = 1.f/(1.f+expf(-sc*l1));
  float p2 = 1.f/(1.f+expf(-sc*l2));
  float p3 = 1.f/(1.f+expf(-sc*l3));
  float s=0.f, s2=0.f;
  for (int c = 0; c < 512; ++c){
    float m = bs[c] + Mm[c][0]*p0 + Mm[c][1]*p1 + Mm[c][2]*p2 + Mm[c][3]*p3;
    s += m; s2 += m*m;
  }
  float mean = s*(1.f/512.f);
  float rs = rsqrtf(s2*(1.f/512.f) - mean*mean + 1e-5f);
  for (int c = 0; c < 512; ++c){
    float m = bs[c] + Mm[c][0]*p0 + Mm[c][1]*p1 + Mm[c][2]*p2 + Mm[c][3]*p3;
    OutY[(size_t)c*cstride + jl] = (m - mean)*rs*gam[c] + bet[c];
  }
}

// ---------------- generic 64x64 column-GEMM: Out = act(W @ X + bias) -------
__global__ __launch_bounds__(256) void gemm64f(
    const float* __restrict__ W, const float* __restrict__ bias,
    const float* __restrict__ X0, int x0_global,
    const float* __restrict__ X1,
    float* __restrict__ Out, int cstride,
    int K, int do_gelu, int j0_global)
{
  __shared__ __align__(16) float Ws[32][64];
  __shared__ __align__(16) float Xs[32][64];
  const int tid = threadIdx.x;
  const int bc = blockIdx.x, rb = blockIdx.y;
  const int tcol = tid & 15, trow = tid >> 4;
  const int wr_r = tid >> 2;           // 0..63
  const int wr_k = (tid & 3) * 8;      // 0,8,16,24
  const int xs_k = tid >> 3;           // 0..31
  const int xs_j = (tid & 7) * 8;      // 0..56
  float acc[4][4];
  #pragma unroll
  for (int i=0;i<4;++i){
    #pragma unroll
    for (int j=0;j<4;++j) acc[i][j]=0.f;
  }
  const float* wrow = W + (size_t)(rb*64 + wr_r)*K;

  for (int k0 = 0; k0 < K; k0 += 32){
    { // stage W panel transposed to k-major
      F8 w = load8f(wrow + k0 + wr_k);
      #pragma unroll
      for (int i=0;i<8;++i) Ws[wr_k + i][wr_r] = w.v[i];
    }
    { // stage X panel
      const float* src; size_t base; size_t stride; int lk = k0;
      if (k0 < 512){
        src = X0;
        if (x0_global){
          int jg = j0_global + bc*64;
          base = (size_t)(jg >> 12) * 2097152 + (size_t)(jg & 4095);
          stride = 4096;
        } else {
          base = (size_t)bc * 64; stride = (size_t)cstride;
        }
      } else {
        src = X1; base = (size_t)bc*64; stride = (size_t)cstride; lk = k0 - 512;
      }
      F8 xv = load8f(src + base + (size_t)(lk + xs_k)*stride + xs_j);
      *(float4*)&Xs[xs_k][xs_j]   = make_float4(xv.v[0],xv.v[1],xv.v[2],xv.v[3]);
      *(float4*)&Xs[xs_k][xs_j+4] = make_float4(xv.v[4],xv.v[5],xv.v[6],xv.v[7]);
    }
    __syncthreads();
    #pragma unroll
    for (int kk = 0; kk < 32; ++kk){
      float4 a  = *(const float4*)&Ws[kk][trow*4];
      float4 bx = *(const float4*)&Xs[kk][tcol*4];
      float av[4] = {a.x,a.y,a.z,a.w};
      float bv[4] = {bx.x,bx.y,bx.z,bx.w};
      #pragma unroll
      for (int i=0;i<4;++i){
        #pragma unroll
        for (int j=0;j<4;++j) acc[i][j] += av[i]*bv[j];
      }
    }
    __syncthreads();
  }
  #pragma unroll
  for (int i=0;i<4;++i){
    int r = rb*64 + trow*4 + i;
    float bb = bias[r];
    float v0 = acc[i][0]+bb, v1 = acc[i][1]+bb, v2 = acc[i][2]+bb, v3 = acc[i][3]+bb;
    if (do_gelu){ v0=gelu_f(v0); v1=gelu_f(v1); v2=gelu_f(v2); v3=gelu_f(v3); }
    *(float4*)(Out + (size_t)r*cstride + (size_t)bc*64 + tcol*4) = make_float4(v0,v1,v2,v3);
  }
}

// ---------------- LN over 512 channels + x residual --------------------------
__global__ __launch_bounds__(256) void k_ln512res(
    const float* __restrict__ In, int cstride,
    const float* __restrict__ gamma, const float* __restrict__ beta,
    const float* __restrict__ Xres, int j0_global,
    float* __restrict__ Out)
{
  __shared__ float gam[512], bet[512];
  const int tid = threadIdx.x;
  for (int c = tid; c < 512; c += 256){ gam[c]=gamma[c]; bet[c]=beta[c]; }
  __syncthreads();
  const int jl = blockIdx.x*256 + tid;
  float s=0.f, s2=0.f;
  for (int c = 0; c < 512; ++c){
    float v = In[(size_t)c*cstride + jl];
    s += v; s2 += v*v;
  }
  float m = s*(1.f/512.f);
  float rs = rsqrtf(s2*(1.f/512.f) - m*m + 1e-5f);
  const int jg = j0_global + jl;
  const size_t xbase = (size_t)(jg>>12)*2097152 + (size_t)(jg&4095);
  for (int c = 0; c < 512; ++c){
    float v = In[(size_t)c*cstride + jl];
    float o = (v - m)*rs*gam[c] + bet[c] + Xres[xbase + (size_t)c*4096];
    Out[(size_t)c*cstride + jl] = o;
  }
}

// ---------------- head: LN64(gl1)+gelu -> 64->16->4->2, softmax ch0 --------
__global__ __launch_bounds__(256) void k_head(
    const float* __restrict__ G, int cstride,
    const float* __restrict__ gl1_g, const float* __restrict__ gl1_b,
    const float* __restrict__ g2_w, const float* __restrict__ g2_b,
    const float* __restrict__ gl2_g, const float* __restrict__ gl2_b,
    const float* __restrict__ g3_w, const float* __restrict__ g3_b,
    const float* __restrict__ gl3_g, const float* __restrict__ gl3_b,
    const float* __restrict__ g4_w, const float* __restrict__ g4_b, int has_g4b,
    float* __restrict__ Outp, int j0_global)
{
  __shared__ float L1g[64], L1b[64];
  __shared__ float W2[16][64], B2v[16], G2v[16], T2v[16];
  __shared__ float W3[4][16], B3v[4], G3v[4], T3v[4];
  __shared__ float W4d[4]; __shared__ float b4d;
  const int tid = threadIdx.x;
  if (tid < 64){ L1g[tid]=gl1_g[tid]; L1b[tid]=gl1_b[tid]; }
  for (int i = tid; i < 1024; i += 256) W2[i>>6][i&63] = g2_w[i];
  if (tid < 16){ B2v[tid]=g2_b[tid]; G2v[tid]=gl2_g[tid]; T2v[tid]=gl2_b[tid]; }
  if (tid < 64) W3[tid>>4][tid&15] = g3_w[tid];
  if (tid < 4){ B3v[tid]=g3_b[tid]; G3v[tid]=gl3_g[tid]; T3v[tid]=gl3_b[tid];
                W4d[tid] = g4_w[tid] - g4_w[4+tid]; }
  if (tid == 0) b4d = has_g4b ? (g4_b[0] - g4_b[1]) : 0.f;
  __syncthreads();
  const int jl = blockIdx.x*256 + tid;
  float a1[64]; float s=0.f;
  #pragma unroll
  for (int c=0;c<64;++c){ a1[c] = G[(size_t)c*cstride + jl]; s += a1[c]; }
  float m = s*(1.f/64.f); float s2=0.f;
  #pragma unroll
  for (int c=0;c<64;++c){ float d=a1[c]-m; s2+=d*d; }
  float rs = rsqrtf(s2*(1.f/64.f)+1e-5f);
  #pragma unroll
  for (int c=0;c<64;++c) a1[c] = gelu_f((a1[c]-m)*rs*L1g[c]+L1b[c]);

  float a2[16]; s=0.f;
  #pragma unroll
  for (int i=0;i<16;++i){
    float acc = B2v[i];
    #pragma unroll
    for (int o=0;o<64;++o) acc += W2[i][o]*a1[o];
    a2[i]=acc; s+=acc;
  }
  m = s*(1.f/16.f); s2=0.f;
  #pragma unroll
  for (int i=0;i<16;++i){ float d=a2[i]-m; s2+=d*d; }
  rs = rsqrtf(s2*(1.f/16.f)+1e-5f);
  float a2g[16];
  #pragma unroll
  for (int i=0;i<16;++i) a2g[i] = gelu_f((a2[i]-m)*rs*G2v[i]+T2v[i]);

  float a3[4]; s=0.f;
  #pragma unroll
  for (int i=0;i<4;++i){
    float acc=B3v[i];
    #pragma unroll
    for (int o=0;o<16;++o) acc += W3[i][o]*a2g[o];
    a3[i]=acc; s+=acc;
  }
  m = s*0.25f; s2=0.f;
  #pragma unroll
  for (int i=0;i<4;++i){ float d=a3[i]-m; s2+=d*d; }
  rs = rsqrtf(s2*0.25f+1e-5f);
  float z = b4d;
  #pragma unroll
  for (int i=0;i<4;++i) z += W4d[i]*gelu_f((a3[i]-m)*rs*G3v[i]+T3v[i]);
  Outp[j0_global + jl] = 1.f/(1.f+expf(-z));   // softmax over 2 channels, ch 0
}

extern "C" void kernel_launch(void* const* d_in, const int* in_sizes, int n_in,
                              void* d_out, int out_size, void* d_ws, size_t ws_size,
                              hipStream_t stream)
{
  const float* gtok  = (const float*)d_in[0];
  const float* x     = (const float*)d_in[1];
  const float* ws1_w = (const float*)d_in[2];
  const float* ws1_b = (const float*)d_in[3];
  const float* ws2_w = (const float*)d_in[4];
  const float* ws2_b = (const float*)d_in[5];
  const float* wc1_w = (const float*)d_in[6];
  const float* wc1_b = (const float*)d_in[7];
  const float* wc2_w = (const float*)d_in[8];
  const float* wc2_b = (const float*)d_in[9];
  const float* q_w   = (const float*)d_in[10];
  const float* q_b   = (const float*)d_in[11];
  const float* k_w   = (const float*)d_in[12];
  const float* v_w   = (const float*)d_in[14];
  const float* v_b   = (const float*)d_in[15];
  const float* merge_w = (const float*)d_in[16];
  const float* merge_b = (const float*)d_in[17];
  const float* m1_w  = (const float*)d_in[18];
  const float* m1_b  = (const float*)d_in[19];
  const float* m2_w  = (const float*)d_in[20];
  const float* m2_b  = (const float*)d_in[21];
  const float* n0_g  = (const float*)d_in[22];
  const float* n0_b  = (const float*)d_in[23];
  const float* n1_g  = (const float*)d_in[24];
  const float* n1_b  = (const float*)d_in[25];
  const float* g1_w  = (const float*)d_in[26];
  const float* g1_b  = (const float*)d_in[27];
  const float* gl1_g = (const float*)d_in[28];
  const float* gl1_b = (const float*)d_in[29];
  const float* g2_w  = (const float*)d_in[30];
  const float* g2_b  = (const float*)d_in[31];
  const float* gl2_g = (const float*)d_in[32];
  const float* gl2_b = (const float*)d_in[33];
  const float* g3_w  = (const float*)d_in[34];
  const float* g3_b  = (const float*)d_in[35];
  const float* gl3_g = (const float*)d_in[36];
  const float* gl3_b = (const float*)d_in[37];
  const float* g4_w  = (const float*)d_in[38];
  const float* g4_b  = (n_in > 39) ? (const float*)d_in[39] : nullptr;

  const int TOT = 65536;  // B*N columns
  const size_t PRE_BYTES = (size_t)16 * PRE_STRIDE * 4;   // 295,936 B
  // per-chunk fp32 buffers: y 512C + t1 1024C + t2 512C + g 64C = 2112C floats
  int C = 65536;
  while (C > 256 && PRE_BYTES + (size_t)8448*C > ws_size) C >>= 1;
  const int nch = TOT / C;

  char* wsb = (char*)d_ws;
  float* PRE = (float*)wsb;
  size_t off = PRE_BYTES;
  float* bufY = (float*)(wsb + off); off += (size_t)512*C*4;   // y, then xd
  float* bufT = (float*)(wsb + off); off += (size_t)1024*C*4;  // t1
  float* bufA = (float*)(wsb + off); off += (size_t)512*C*4;   // t2
  float* bufG = (float*)(wsb + off); off += (size_t)64*C*4;    // g1 out

  dim3 blk(256);
  hipLaunchKernelGGL(k0_pre, dim3(16), blk, 0, stream,
      gtok, ws1_w, ws1_b, ws2_w, ws2_b, wc1_w, wc1_b, wc2_w, wc2_b,
      q_w, q_b, k_w, v_w, v_b, merge_w, merge_b, PRE);

  for (int ch = 0; ch < nch; ++ch){
    const int j0 = ch * C;
    dim3 g16(C/64, 16), g8(C/64, 8), g1g(C/64, 1);
    dim3 cols(C/256);
    // y = LN_c(attn-merge(x); n0)        -> bufY
    hipLaunchKernelGGL(k1_amln, cols, blk, 0, stream,
        x, PRE, n0_g, n0_b, j0, C, bufY);
    // t1 = gelu(m1 @ [x; y] + b)         -> bufT
    hipLaunchKernelGGL(gemm64f, g16, blk, 0, stream,
        m1_w, m1_b, x, 1, bufY, bufT, C, 1024, 1, j0);
    // t2 = m2 @ t1 + b                   -> bufA
    hipLaunchKernelGGL(gemm64f, g8, blk, 0, stream,
        m2_w, m2_b, bufT, 0, bufT + (size_t)512*C, bufA, C, 1024, 0, j0);
    // xd = x + LN_c(t2; n1)              -> bufY
    hipLaunchKernelGGL(k_ln512res, cols, blk, 0, stream,
        bufA, C, n1_g, n1_b, x, j0, bufY);
    // g1raw = g1_w @ xd + b              -> bufG
    hipLaunchKernelGGL(gemm64f, g1g, blk, 0, stream,
        g1_w, g1_b, bufY, 0, (const float*)nullptr, bufG, C, 512, 0, j0);
    // head: LN64+gelu -> 16 -> 4 -> 2 -> sigmoid -> d_out
    hipLaunchKernelGGL(k_head, cols, blk, 0, stream,
        bufG, C, gl1_g, gl1_b, g2_w, g2_b, gl2_g, gl2_b,
        g3_w, g3_b, gl3_g, gl3_b,
        g4_w, g4_b ? g4_b : g4_w, g4_b ? 1 : 0, (float*)d_out, j0);
  }
}

// Round 3
// 1918.557 us; speedup vs baseline: 2.2123x; 2.2123x over previous
//
#include <hip/hip_runtime.h>
#include <math.h>

typedef unsigned short u16;
typedef __attribute__((ext_vector_type(8))) short bfrag;   // 8 bf16 (4 VGPRs)
typedef __attribute__((ext_vector_type(4))) float f32x4;

__device__ __forceinline__ float gelu_f(float x){
  return 0.5f * x * (1.0f + erff(x * 0.70710678118654752440f));
}
__device__ __forceinline__ u16 f2bf(float f){
  union { float f; unsigned int i; } c; c.f = f;
  unsigned int i = c.i;
  return (u16)((i + 0x7FFFu + ((i >> 16) & 1u)) >> 16);
}

struct F8 { float v[8]; };
__device__ __forceinline__ F8 load8f(const float* p){
  float4 a = *(const float4*)p; float4 b = *(const float4*)(p + 4);
  F8 r; r.v[0]=a.x; r.v[1]=a.y; r.v[2]=a.z; r.v[3]=a.w;
  r.v[4]=b.x; r.v[5]=b.y; r.v[6]=b.z; r.v[7]=b.w; return r;
}

// PRE layout per batch (stride 4624 floats):
//   [0..2047] wdiff[h][i] | [2048..2051] beta[h] | [2064..2575] base[r]
//   [2576..4623] M[r][h] (r*4+h)
#define PRE_STRIDE 4624

// ---------------- K0: group-token MLPs -> k,v -> rank-4 attn precompute ----
__global__ __launch_bounds__(256) void k0_pre(
    const float* __restrict__ gtok,
    const float* __restrict__ ws1_w, const float* __restrict__ ws1_b,
    const float* __restrict__ ws2_w, const float* __restrict__ ws2_b,
    const float* __restrict__ wc1_w, const float* __restrict__ wc1_b,
    const float* __restrict__ wc2_w, const float* __restrict__ wc2_b,
    const float* __restrict__ q_w, const float* __restrict__ q_b,
    const float* __restrict__ k_w,
    const float* __restrict__ v_w, const float* __restrict__ v_b,
    const float* __restrict__ merge_w, const float* __restrict__ merge_b,
    float* __restrict__ PRE)
{
  __shared__ float gt[512][2];
  __shared__ float hid[2048];
  __shared__ float sw1[256][2]; __shared__ float sb1[256];
  __shared__ float sw2[2][256];
  __shared__ float dk[512], dv[512], v1l[512];
  const int b = blockIdx.x;
  const int t = threadIdx.x;
  sw1[t][0] = ws1_w[2*t]; sw1[t][1] = ws1_w[2*t+1];
  sb1[t] = ws1_b[t];
  sw2[0][t] = ws2_w[t]; sw2[1][t] = ws2_w[256+t];
  for (int d = t; d < 512; d += 256){
    gt[d][0] = gtok[b*1024 + 2*d]; gt[d][1] = gtok[b*1024 + 2*d + 1];
  }
  __syncthreads();
  const float s2b0 = ws2_b[0], s2b1 = ws2_b[1];
  for (int j = t; j < 512; j += 256){
    float a0 = gt[j][0], a1 = gt[j][1];
    float s0 = s2b0, s1 = s2b1;
    #pragma unroll 4
    for (int o = 0; o < 256; ++o){
      float h = gelu_f(sw1[o][0]*a0 + sw1[o][1]*a1 + sb1[o]);
      s0 += sw2[0][o]*h; s1 += sw2[1][o]*h;
    }
    gt[j][0] = a0 + s0; gt[j][1] = a1 + s1;
  }
  __syncthreads();
  for (int tt = 0; tt < 2; ++tt){
    for (int o = t; o < 2048; o += 256){
      const float* wr = wc1_w + (size_t)o*512;
      float acc = wc1_b[o];
      for (int d = 0; d < 512; d += 8){
        F8 w = load8f(wr + d);
        #pragma unroll
        for (int i = 0; i < 8; ++i) acc += w.v[i]*gt[d+i][tt];
      }
      hid[o] = gelu_f(acc);
    }
    __syncthreads();
    for (int d = t; d < 512; d += 256){
      const float* wr = wc2_w + (size_t)d*2048;
      float acc = wc2_b[d];
      for (int o = 0; o < 2048; o += 8){
        F8 w = load8f(wr + o);
        #pragma unroll
        for (int i = 0; i < 8; ++i) acc += w.v[i]*hid[o+i];
      }
      gt[d][tt] += acc;
    }
    __syncthreads();
  }
  for (int c = t; c < 512; c += 256){
    const float* kr = k_w + (size_t)c*512;
    const float* vr = v_w + (size_t)c*512;
    float k0a=0.f,k1a=0.f,v0a=0.f,v1a=0.f;
    for (int d = 0; d < 512; d += 8){
      F8 kw = load8f(kr + d); F8 vw = load8f(vr + d);
      #pragma unroll
      for (int i = 0; i < 8; ++i){
        float g0 = gt[d+i][0], g1 = gt[d+i][1];
        k0a += kw.v[i]*g0; k1a += kw.v[i]*g1;
        v0a += vw.v[i]*g0; v1a += vw.v[i]*g1;
      }
    }
    dk[c] = k0a - k1a; dv[c] = v0a - v1a; v1l[c] = v1a + v_b[c];
  }
  __syncthreads();
  float* P = PRE + (size_t)b * PRE_STRIDE;
  for (int i = t; i < 512; i += 256){
    float w0=0.f,w1=0.f,w2=0.f,w3=0.f;
    for (int c = 0; c < 512; c += 4){
      w0 += dk[c]  *q_w[(size_t)(c)  *512 + i];
      w1 += dk[c+1]*q_w[(size_t)(c+1)*512 + i];
      w2 += dk[c+2]*q_w[(size_t)(c+2)*512 + i];
      w3 += dk[c+3]*q_w[(size_t)(c+3)*512 + i];
    }
    P[0*512+i]=w0; P[1*512+i]=w1; P[2*512+i]=w2; P[3*512+i]=w3;
  }
  if (t < 4){
    float bsum = 0.f;
    for (int c = t; c < 512; c += 4) bsum += dk[c]*q_b[c];
    P[2048 + t] = bsum;
  }
  for (int r = t; r < 512; r += 256){
    const float* mw = merge_w + (size_t)r*512;
    float ab = merge_b[r];
    float m0=0.f,m1=0.f,m2=0.f,m3=0.f;
    for (int c = 0; c < 512; c += 4){
      float a0=mw[c],a1=mw[c+1],a2=mw[c+2],a3=mw[c+3];
      ab += a0*v1l[c]+a1*v1l[c+1]+a2*v1l[c+2]+a3*v1l[c+3];
      m0 += a0*dv[c]; m1 += a1*dv[c+1]; m2 += a2*dv[c+2]; m3 += a3*dv[c+3];
    }
    P[2064 + r] = ab;
    *(float4*)&P[2576 + r*4] = make_float4(m0,m1,m2,m3);
  }
}

// ---------------- convert fp32 -> bf16 (flat) ------------------------------
__global__ __launch_bounds__(256) void kcvt(const float* __restrict__ s,
                                            u16* __restrict__ d, int n8)
{
  int g = blockIdx.x*256 + threadIdx.x;
  if (g >= n8) return;
  F8 v = load8f(s + (size_t)g*8);
  u16 o[8];
  #pragma unroll
  for (int i=0;i<8;++i) o[i] = f2bf(v.v[i]);
  *(uint4*)(d + (size_t)g*8) = *(uint4*)o;
}

// ---------------- convert x (b,512,4096) -> XYb rows 0..511 (bf16) ---------
__global__ __launch_bounds__(256) void kcvt_x(const float* __restrict__ x,
                                              u16* __restrict__ XYb,
                                              int j0, int C, int shRow)
{ // shRow = log2(C/8); grid covers 512*C/8 threads
  int g = blockIdx.x*256 + threadIdx.x;
  int k = g >> shRow;
  int jl8 = g - (k << shRow);
  int j = j0 + jl8*8;
  int b = j >> 12, n = j & 4095;
  const float* src = x + (size_t)b*2097152 + (size_t)k*4096 + n;
  F8 v = load8f(src);
  u16 o[8];
  #pragma unroll
  for (int i=0;i<8;++i) o[i] = f2bf(v.v[i]);
  *(uint4*)(XYb + (size_t)k*C + (size_t)jl8*8) = *(uint4*)o;
}

// ---------------- K1: fused attn+merge+LN(n0), writes y as bf16 ------------
__global__ __launch_bounds__(256) void k1_amln(
    const float* __restrict__ x, const float* __restrict__ PRE,
    const float* __restrict__ n0_g, const float* __restrict__ n0_b,
    int j0_global, int cstride, u16* __restrict__ OutY)
{
  __shared__ float wd[4][512];
  __shared__ float bs[512];
  __shared__ float Mm[512][4];
  __shared__ float gam[512], bet[512];
  __shared__ float beta4[4];
  const int tid = threadIdx.x;
  const int jl = blockIdx.x*256 + tid;
  const int jg = j0_global + jl;
  const int b = jg >> 12, n = jg & 4095;
  const float* P = PRE + (size_t)b * PRE_STRIDE;
  for (int i = tid; i < 2048; i += 256) wd[i>>9][i&511] = P[i];
  if (tid < 4) beta4[tid] = P[2048 + tid];
  for (int i = tid; i < 512; i += 256){
    bs[i] = P[2064 + i]; gam[i] = n0_g[i]; bet[i] = n0_b[i];
  }
  for (int i = tid; i < 2048; i += 256) Mm[i>>2][i&3] = P[2576 + i];
  __syncthreads();
  const float* xc = x + (size_t)b*2097152 + n;
  float l0=beta4[0], l1=beta4[1], l2=beta4[2], l3=beta4[3];
  for (int i = 0; i < 512; ++i){
    float xv = xc[(size_t)i*4096];
    l0 += wd[0][i]*xv; l1 += wd[1][i]*xv; l2 += wd[2][i]*xv; l3 += wd[3][i]*xv;
  }
  const float sc = 0.0883883476483184405f;
  float p0 = 1.f/(1.f+expf(-sc*l0));
  float p1 = 1.f/(1.f+expf(-sc*l1));
  float p2 = 1.f/(1.f+expf(-sc*l2));
  float p3 = 1.f/(1.f+expf(-sc*l3));
  float s=0.f, s2=0.f;
  for (int c = 0; c < 512; ++c){
    float m = bs[c] + Mm[c][0]*p0 + Mm[c][1]*p1 + Mm[c][2]*p2 + Mm[c][3]*p3;
    s += m; s2 += m*m;
  }
  float mean = s*(1.f/512.f);
  float rs = rsqrtf(s2*(1.f/512.f) - mean*mean + 1e-5f);
  for (int c = 0; c < 512; ++c){
    float m = bs[c] + Mm[c][0]*p0 + Mm[c][1]*p1 + Mm[c][2]*p2 + Mm[c][3]*p3;
    OutY[(size_t)c*cstride + jl] = f2bf((m - mean)*rs*gam[c] + bet[c]);
  }
}

// ---------------- MFMA GEMM: Out = act(Wb @ Xb + bias), 128x128 tile -------
// Wb: bf16 [M][K] row-major; Xb: bf16 [K][C] row-major. BK=32.
// A_lds/B_lds: [row128][k32] bf16; frag: lane m=lane&15, k=(lane>>4)*8+j.
// C/D: col=lane&15, row=(lane>>4)*4+reg  [m89-verified].
__global__ __launch_bounds__(256) void mfma_gemm(
    const u16* __restrict__ Wb, const float* __restrict__ bias,
    const u16* __restrict__ Xb, int K, int C,
    float* __restrict__ OutF, u16* __restrict__ OutH, int do_gelu)
{
  __shared__ __align__(16) u16 Asl[128*32];
  __shared__ __align__(16) u16 Bsl[128*32];
  const int tid = threadIdx.x;
  const int lane = tid & 63, w = tid >> 6;
  const int bj = blockIdx.x, bi = blockIdx.y;
  const int roff = (w >> 1) * 64;
  const int noff = (w & 1) * 64;
  const int lm = lane & 15, quad = lane >> 4;

  f32x4 acc[4][4];
  #pragma unroll
  for (int i=0;i<4;++i){
    #pragma unroll
    for (int j=0;j<4;++j) acc[i][j] = (f32x4){0.f,0.f,0.f,0.f};
  }
  // A staging: thread -> row tid>>1, elems (tid&1)*16 .. +15
  const int ar = tid >> 1;
  const int akc = (tid & 1) * 16;
  const u16* aG = Wb + (size_t)(bi*128 + ar)*K + akc;
  // B staging: thread -> k-pair tid>>4, col group tid&15 (8 cols)
  const int jg = tid & 15;
  const int kp = tid >> 4;
  const u16* bG = Xb + (size_t)(2*kp)*C + (size_t)bj*128 + (size_t)jg*8;

  for (int k0 = 0; k0 < K; k0 += 32){
    uint4 a0 = *(const uint4*)(aG + k0);
    uint4 a1 = *(const uint4*)(aG + k0 + 8);
    uint4 r0 = *(const uint4*)(bG + (size_t)k0*C);
    uint4 r1 = *(const uint4*)(bG + (size_t)(k0+1)*C);
    *(uint4*)&Asl[ar*32 + akc]     = a0;
    *(uint4*)&Asl[ar*32 + akc + 8] = a1;
    const u16* s0 = (const u16*)&r0;
    const u16* s1 = (const u16*)&r1;
    #pragma unroll
    for (int jj = 0; jj < 8; ++jj){   // transpose: Bsl[n][k] pairs
      unsigned int dw = (unsigned int)s0[jj] | ((unsigned int)s1[jj] << 16);
      *(unsigned int*)&Bsl[(jg*8 + jj)*32 + 2*kp] = dw;
    }
    __syncthreads();
    bfrag av[4], bv[4];
    #pragma unroll
    for (int i=0;i<4;++i)
      av[i] = *(const bfrag*)&Asl[(roff + 16*i + lm)*32 + quad*8];
    #pragma unroll
    for (int j=0;j<4;++j)
      bv[j] = *(const bfrag*)&Bsl[(noff + 16*j + lm)*32 + quad*8];
    #pragma unroll
    for (int i=0;i<4;++i){
      #pragma unroll
      for (int j=0;j<4;++j)
        acc[i][j] = __builtin_amdgcn_mfma_f32_16x16x32_bf16(av[i], bv[j], acc[i][j], 0,0,0);
    }
    __syncthreads();
  }
  const size_t colBase = (size_t)bj*128 + noff + lm;
  #pragma unroll
  for (int i=0;i<4;++i){
    int Rb = bi*128 + roff + 16*i + quad*4;
    #pragma unroll
    for (int r=0;r<4;++r){
      int R = Rb + r;
      float bb = bias[R];
      #pragma unroll
      for (int j=0;j<4;++j){
        float v = acc[i][j][r] + bb;
        if (do_gelu) v = gelu_f(v);
        if (OutH) OutH[(size_t)R*C + colBase + 16*j] = f2bf(v);
        else      OutF[(size_t)R*C + colBase + 16*j] = v;
      }
    }
  }
}

// ---------------- gemm64f (fp32) kept for the small g1 GEMM ----------------
__global__ __launch_bounds__(256) void gemm64f(
    const float* __restrict__ W, const float* __restrict__ bias,
    const float* __restrict__ X0,
    float* __restrict__ Out, int cstride, int K)
{
  __shared__ __align__(16) float Ws[32][64];
  __shared__ __align__(16) float Xs[32][64];
  const int tid = threadIdx.x;
  const int bc = blockIdx.x, rb = blockIdx.y;
  const int tcol = tid & 15, trow = tid >> 4;
  const int wr_r = tid >> 2;
  const int wr_k = (tid & 3) * 8;
  const int xs_k = tid >> 3;
  const int xs_j = (tid & 7) * 8;
  float acc[4][4];
  #pragma unroll
  for (int i=0;i<4;++i){
    #pragma unroll
    for (int j=0;j<4;++j) acc[i][j]=0.f;
  }
  const float* wrow = W + (size_t)(rb*64 + wr_r)*K;
  for (int k0 = 0; k0 < K; k0 += 32){
    {
      F8 w = load8f(wrow + k0 + wr_k);
      #pragma unroll
      for (int i=0;i<8;++i) Ws[wr_k + i][wr_r] = w.v[i];
    }
    {
      F8 xv = load8f(X0 + (size_t)bc*64 + (size_t)(k0 + xs_k)*cstride + xs_j);
      *(float4*)&Xs[xs_k][xs_j]   = make_float4(xv.v[0],xv.v[1],xv.v[2],xv.v[3]);
      *(float4*)&Xs[xs_k][xs_j+4] = make_float4(xv.v[4],xv.v[5],xv.v[6],xv.v[7]);
    }
    __syncthreads();
    #pragma unroll
    for (int kk = 0; kk < 32; ++kk){
      float4 a  = *(const float4*)&Ws[kk][trow*4];
      float4 bx = *(const float4*)&Xs[kk][tcol*4];
      float av[4] = {a.x,a.y,a.z,a.w};
      float bv[4] = {bx.x,bx.y,bx.z,bx.w};
      #pragma unroll
      for (int i=0;i<4;++i){
        #pragma unroll
        for (int j=0;j<4;++j) acc[i][j] += av[i]*bv[j];
      }
    }
    __syncthreads();
  }
  #pragma unroll
  for (int i=0;i<4;++i){
    int r = rb*64 + trow*4 + i;
    float bb = bias[r];
    *(float4*)(Out + (size_t)r*cstride + (size_t)bc*64 + tcol*4) =
        make_float4(acc[i][0]+bb, acc[i][1]+bb, acc[i][2]+bb, acc[i][3]+bb);
  }
}

// ---------------- LN over 512 channels + x residual ------------------------
__global__ __launch_bounds__(256) void k_ln512res(
    const float* __restrict__ In, int cstride,
    const float* __restrict__ gamma, const float* __restrict__ beta,
    const float* __restrict__ Xres, int j0_global,
    float* __restrict__ Out)
{
  __shared__ float gam[512], bet[512];
  const int tid = threadIdx.x;
  for (int c = tid; c < 512; c += 256){ gam[c]=gamma[c]; bet[c]=beta[c]; }
  __syncthreads();
  const int jl = blockIdx.x*256 + tid;
  float s=0.f, s2=0.f;
  for (int c = 0; c < 512; ++c){
    float v = In[(size_t)c*cstride + jl];
    s += v; s2 += v*v;
  }
  float m = s*(1.f/512.f);
  float rs = rsqrtf(s2*(1.f/512.f) - m*m + 1e-5f);
  const int jg = j0_global + jl;
  const size_t xbase = (size_t)(jg>>12)*2097152 + (size_t)(jg&4095);
  for (int c = 0; c < 512; ++c){
    float v = In[(size_t)c*cstride + jl];
    Out[(size_t)c*cstride + jl] = (v - m)*rs*gam[c] + bet[c] + Xres[xbase + (size_t)c*4096];
  }
}

// ---------------- head: LN64+gelu -> 16 -> 4 -> 2, softmax ch0 -------------
__global__ __launch_bounds__(256) void k_head(
    const float* __restrict__ G, int cstride,
    const float* __restrict__ gl1_g, const float* __restrict__ gl1_b,
    const float* __restrict__ g2_w, const float* __restrict__ g2_b,
    const float* __restrict__ gl2_g, const float* __restrict__ gl2_b,
    const float* __restrict__ g3_w, const float* __restrict__ g3_b,
    const float* __restrict__ gl3_g, const float* __restrict__ gl3_b,
    const float* __restrict__ g4_w, const float* __restrict__ g4_b, int has_g4b,
    float* __restrict__ Outp, int j0_global)
{
  __shared__ float L1g[64], L1b[64];
  __shared__ float W2[16][64], B2v[16], G2v[16], T2v[16];
  __shared__ float W3[4][16], B3v[4], G3v[4], T3v[4];
  __shared__ float W4d[4]; __shared__ float b4d;
  const int tid = threadIdx.x;
  if (tid < 64){ L1g[tid]=gl1_g[tid]; L1b[tid]=gl1_b[tid]; }
  for (int i = tid; i < 1024; i += 256) W2[i>>6][i&63] = g2_w[i];
  if (tid < 16){ B2v[tid]=g2_b[tid]; G2v[tid]=gl2_g[tid]; T2v[tid]=gl2_b[tid]; }
  if (tid < 64) W3[tid>>4][tid&15] = g3_w[tid];
  if (tid < 4){ B3v[tid]=g3_b[tid]; G3v[tid]=gl3_g[tid]; T3v[tid]=gl3_b[tid];
                W4d[tid] = g4_w[tid] - g4_w[4+tid]; }
  if (tid == 0) b4d = has_g4b ? (g4_b[0] - g4_b[1]) : 0.f;
  __syncthreads();
  const int jl = blockIdx.x*256 + tid;
  float a1[64]; float s=0.f;
  #pragma unroll
  for (int c=0;c<64;++c){ a1[c] = G[(size_t)c*cstride + jl]; s += a1[c]; }
  float m = s*(1.f/64.f); float s2=0.f;
  #pragma unroll
  for (int c=0;c<64;++c){ float d=a1[c]-m; s2+=d*d; }
  float rs = rsqrtf(s2*(1.f/64.f)+1e-5f);
  #pragma unroll
  for (int c=0;c<64;++c) a1[c] = gelu_f((a1[c]-m)*rs*L1g[c]+L1b[c]);

  float a2[16]; s=0.f;
  #pragma unroll
  for (int i=0;i<16;++i){
    float acc = B2v[i];
    #pragma unroll
    for (int o=0;o<64;++o) acc += W2[i][o]*a1[o];
    a2[i]=acc; s+=acc;
  }
  m = s*(1.f/16.f); s2=0.f;
  #pragma unroll
  for (int i=0;i<16;++i){ float d=a2[i]-m; s2+=d*d; }
  rs = rsqrtf(s2*(1.f/16.f)+1e-5f);
  float a2g[16];
  #pragma unroll
  for (int i=0;i<16;++i) a2g[i] = gelu_f((a2[i]-m)*rs*G2v[i]+T2v[i]);

  float a3[4]; s=0.f;
  #pragma unroll
  for (int i=0;i<4;++i){
    float acc=B3v[i];
    #pragma unroll
    for (int o=0;o<16;++o) acc += W3[i][o]*a2g[o];
    a3[i]=acc; s+=acc;
  }
  m = s*0.25f; s2=0.f;
  #pragma unroll
  for (int i=0;i<4;++i){ float d=a3[i]-m; s2+=d*d; }
  rs = rsqrtf(s2*0.25f+1e-5f);
  float z = b4d;
  #pragma unroll
  for (int i=0;i<4;++i) z += W4d[i]*gelu_f((a3[i]-m)*rs*G3v[i]+T3v[i]);
  Outp[j0_global + jl] = 1.f/(1.f+expf(-z));
}

extern "C" void kernel_launch(void* const* d_in, const int* in_sizes, int n_in,
                              void* d_out, int out_size, void* d_ws, size_t ws_size,
                              hipStream_t stream)
{
  const float* gtok  = (const float*)d_in[0];
  const float* x     = (const float*)d_in[1];
  const float* ws1_w = (const float*)d_in[2];
  const float* ws1_b = (const float*)d_in[3];
  const float* ws2_w = (const float*)d_in[4];
  const float* ws2_b = (const float*)d_in[5];
  const float* wc1_w = (const float*)d_in[6];
  const float* wc1_b = (const float*)d_in[7];
  const float* wc2_w = (const float*)d_in[8];
  const float* wc2_b = (const float*)d_in[9];
  const float* q_w   = (const float*)d_in[10];
  const float* q_b   = (const float*)d_in[11];
  const float* k_w   = (const float*)d_in[12];
  const float* v_w   = (const float*)d_in[14];
  const float* v_b   = (const float*)d_in[15];
  const float* merge_w = (const float*)d_in[16];
  const float* merge_b = (const float*)d_in[17];
  const float* m1_w  = (const float*)d_in[18];
  const float* m1_b  = (const float*)d_in[19];
  const float* m2_w  = (const float*)d_in[20];
  const float* m2_b  = (const float*)d_in[21];
  const float* n0_g  = (const float*)d_in[22];
  const float* n0_b  = (const float*)d_in[23];
  const float* n1_g  = (const float*)d_in[24];
  const float* n1_b  = (const float*)d_in[25];
  const float* g1_w  = (const float*)d_in[26];
  const float* g1_b  = (const float*)d_in[27];
  const float* gl1_g = (const float*)d_in[28];
  const float* gl1_b = (const float*)d_in[29];
  const float* g2_w  = (const float*)d_in[30];
  const float* g2_b  = (const float*)d_in[31];
  const float* gl2_g = (const float*)d_in[32];
  const float* gl2_b = (const float*)d_in[33];
  const float* g3_w  = (const float*)d_in[34];
  const float* g3_b  = (const float*)d_in[35];
  const float* gl3_g = (const float*)d_in[36];
  const float* gl3_b = (const float*)d_in[37];
  const float* g4_w  = (const float*)d_in[38];
  const float* g4_b  = (n_in > 39) ? (const float*)d_in[39] : nullptr;

  const int TOT = 65536;
  const size_t PRE_BYTES = (size_t)16 * PRE_STRIDE * 4;     // 295,936 (256-aligned)
  const size_t WB1_BYTES = (size_t)1024*1024*2;             // m1_w bf16
  const size_t WB2_BYTES = (size_t)512*1024*2;              // m2_w bf16
  const size_t FIXED = PRE_BYTES + WB1_BYTES + WB2_BYTES;
  // per-chunk: R1 (XYb bf16 / t2 fp32) 2048C + R2 (T1b bf16 / xd fp32) 2048C + G 256C
  int C = 65536;
  while (C > 4096 && FIXED + (size_t)4352*C > ws_size) C >>= 1;
  const int nch = TOT / C;
  int shRow = 0; { int t = C >> 3; while ((1 << shRow) < t) ++shRow; }  // log2(C/8)

  char* wsb = (char*)d_ws;
  float* PRE = (float*)wsb;
  u16* Wb1 = (u16*)(wsb + PRE_BYTES);
  u16* Wb2 = (u16*)(wsb + PRE_BYTES + WB1_BYTES);
  size_t off = FIXED;
  char* R1 = wsb + off; off += (size_t)2048*C;
  char* R2 = wsb + off; off += (size_t)2048*C;
  float* bufG = (float*)(wsb + off); off += (size_t)256*C;

  dim3 blk(256);
  // weight conversions (once per call)
  hipLaunchKernelGGL(kcvt, dim3((1024*1024/8 + 255)/256), blk, 0, stream, m1_w, Wb1, 1024*1024/8);
  hipLaunchKernelGGL(kcvt, dim3((512*1024/8 + 255)/256), blk, 0, stream, m2_w, Wb2, 512*1024/8);
  hipLaunchKernelGGL(k0_pre, dim3(16), blk, 0, stream,
      gtok, ws1_w, ws1_b, ws2_w, ws2_b, wc1_w, wc1_b, wc2_w, wc2_b,
      q_w, q_b, k_w, v_w, v_b, merge_w, merge_b, PRE);

  for (int ch = 0; ch < nch; ++ch){
    const int j0 = ch * C;
    u16* XYb = (u16*)R1;            // [1024][C] bf16: rows 0-511 = x, 512+ = y
    u16* T1b = (u16*)R2;            // [1024][C] bf16
    float* t2 = (float*)R1;         // [512][C] fp32 (aliases XYb after use)
    float* xd = (float*)R2;         // [512][C] fp32 (aliases T1b after use)
    dim3 cols(C/256);
    // x -> bf16 rows 0..511 of XYb
    hipLaunchKernelGGL(kcvt_x, dim3(512*(C/8)/256), blk, 0, stream, x, XYb, j0, C, shRow);
    // y = LN_c(attn-merge(x); n0) -> rows 512..1023 (bf16)
    hipLaunchKernelGGL(k1_amln, cols, blk, 0, stream,
        x, PRE, n0_g, n0_b, j0, C, XYb + (size_t)512*C);
    // t1 = gelu(m1 @ XYb + b) -> T1b (bf16)
    hipLaunchKernelGGL(mfma_gemm, dim3(C/128, 8), blk, 0, stream,
        Wb1, m1_b, XYb, 1024, C, (float*)nullptr, T1b, 1);
    // t2 = m2 @ t1 + b -> fp32 (into R1)
    hipLaunchKernelGGL(mfma_gemm, dim3(C/128, 4), blk, 0, stream,
        Wb2, m2_b, T1b, 1024, C, t2, (u16*)nullptr, 0);
    // xd = x + LN_c(t2; n1) -> fp32 (into R2)
    hipLaunchKernelGGL(k_ln512res, cols, blk, 0, stream,
        t2, C, n1_g, n1_b, x, j0, xd);
    // g1raw = g1_w @ xd + b (fp32 VALU gemm, small)
    hipLaunchKernelGGL(gemm64f, dim3(C/64, 1), blk, 0, stream,
        g1_w, g1_b, xd, bufG, C, 512);
    // head
    hipLaunchKernelGGL(k_head, cols, blk, 0, stream,
        bufG, C, gl1_g, gl1_b, g2_w, g2_b, gl2_g, gl2_b,
        g3_w, g3_b, gl3_g, gl3_b,
        g4_w, g4_b ? g4_b : g4_w, g4_b ? 1 : 0, (float*)d_out, j0);
  }
}

// Round 4
// 1408.193 us; speedup vs baseline: 3.0140x; 1.3624x over previous
//
#include <hip/hip_runtime.h>
#include <math.h>

typedef unsigned short u16;
typedef __attribute__((ext_vector_type(8))) short bfrag;   // 8 bf16 (4 VGPRs)
typedef __attribute__((ext_vector_type(4))) float f32x4;

__device__ __forceinline__ float gelu_f(float x){
  return 0.5f * x * (1.0f + erff(x * 0.70710678118654752440f));
}
__device__ __forceinline__ u16 f2bf(float f){
  union { float f; unsigned int i; } c; c.f = f;
  unsigned int i = c.i;
  return (u16)((i + 0x7FFFu + ((i >> 16) & 1u)) >> 16);
}

struct F8 { float v[8]; };
__device__ __forceinline__ F8 load8f(const float* p){
  float4 a = *(const float4*)p; float4 b = *(const float4*)(p + 4);
  F8 r; r.v[0]=a.x; r.v[1]=a.y; r.v[2]=a.z; r.v[3]=a.w;
  r.v[4]=b.x; r.v[5]=b.y; r.v[6]=b.z; r.v[7]=b.w; return r;
}

// PRE layout per batch (stride 4624 floats):
//   [0..2047] wdiff[h][i] | [2048..2051] beta[h] | [2064..2575] base[r]
//   [2576..4623] M[r][h] (r*4+h)
#define PRE_STRIDE 4624

// ============ k0 phase A: mlp_s (2->256->2) + residual -> GT1 ==============
// grid (16,2), block 256: thread = position j = by*256+tid
__global__ __launch_bounds__(256) void k0a_mlps(
    const float* __restrict__ gtok,
    const float* __restrict__ ws1_w, const float* __restrict__ ws1_b,
    const float* __restrict__ ws2_w, const float* __restrict__ ws2_b,
    float* __restrict__ GT1)
{
  __shared__ float sw1[256][2]; __shared__ float sb1[256];
  __shared__ float sw2[2][256];
  const int b = blockIdx.x;
  const int t = threadIdx.x;
  sw1[t][0] = ws1_w[2*t]; sw1[t][1] = ws1_w[2*t+1];
  sb1[t] = ws1_b[t];
  sw2[0][t] = ws2_w[t]; sw2[1][t] = ws2_w[256+t];
  __syncthreads();
  const int j = blockIdx.y*256 + t;
  const float a0 = gtok[b*1024 + 2*j], a1 = gtok[b*1024 + 2*j + 1];
  float s0 = ws2_b[0], s1 = ws2_b[1];
  #pragma unroll 4
  for (int o = 0; o < 256; ++o){
    float h = gelu_f(sw1[o][0]*a0 + sw1[o][1]*a1 + sb1[o]);
    s0 += sw2[0][o]*h; s1 += sw2[1][o]*h;
  }
  GT1[b*1024 + 2*j]     = a0 + s0;
  GT1[b*1024 + 2*j + 1] = a1 + s1;
}

// ============ k0 phase B: fc1 of mlp_c (512->2048), both tokens -> HID ======
// grid (16,8), block 256: thread = output o = by*256+tid
__global__ __launch_bounds__(256) void k0b_fc1(
    const float* __restrict__ GT1,
    const float* __restrict__ wc1_w, const float* __restrict__ wc1_b,
    float* __restrict__ HID)
{
  __shared__ float g[1024];   // g[d*2+tt]
  const int b = blockIdx.x;
  const int t = threadIdx.x;
  for (int i = t; i < 1024; i += 256) g[i] = GT1[b*1024 + i];
  __syncthreads();
  const int o = blockIdx.y*256 + t;
  const float* wr = wc1_w + (size_t)o*512;
  float acc0 = wc1_b[o], acc1 = acc0;
  for (int d = 0; d < 512; d += 8){
    F8 w = load8f(wr + d);
    #pragma unroll
    for (int i = 0; i < 8; ++i){
      acc0 += w.v[i]*g[(d+i)*2];
      acc1 += w.v[i]*g[(d+i)*2+1];
    }
  }
  HID[b*4096 + o]        = gelu_f(acc0);
  HID[b*4096 + 2048 + o] = gelu_f(acc1);
}

// ============ k0 phase C: fc2 of mlp_c (2048->512) + residual -> GT2 ========
// grid (16,2), block 256: thread = channel d = by*256+tid
__global__ __launch_bounds__(256) void k0c_fc2(
    const float* __restrict__ GT1, const float* __restrict__ HID,
    const float* __restrict__ wc2_w, const float* __restrict__ wc2_b,
    float* __restrict__ GT2)
{
  __shared__ float h0[2048], h1[2048];
  const int b = blockIdx.x;
  const int t = threadIdx.x;
  for (int i = t; i < 2048; i += 256){
    h0[i] = HID[b*4096 + i]; h1[i] = HID[b*4096 + 2048 + i];
  }
  __syncthreads();
  const int d = blockIdx.y*256 + t;
  const float* wr = wc2_w + (size_t)d*2048;
  float acc0 = wc2_b[d], acc1 = acc0;
  for (int o = 0; o < 2048; o += 8){
    F8 w = load8f(wr + o);
    #pragma unroll
    for (int i = 0; i < 8; ++i){
      acc0 += w.v[i]*h0[o+i];
      acc1 += w.v[i]*h1[o+i];
    }
  }
  GT2[b*1024 + 2*d]     = GT1[b*1024 + 2*d]     + acc0;
  GT2[b*1024 + 2*d + 1] = GT1[b*1024 + 2*d + 1] + acc1;
}

// ============ k0 phase D: k,v -> dk, dv, v1l ================================
// grid (16,2), block 256: thread = channel c = by*256+tid
__global__ __launch_bounds__(256) void k0d_kv(
    const float* __restrict__ GT2,
    const float* __restrict__ k_w,
    const float* __restrict__ v_w, const float* __restrict__ v_b,
    float* __restrict__ DK, float* __restrict__ DV, float* __restrict__ V1L)
{
  __shared__ float g[1024];
  const int b = blockIdx.x;
  const int t = threadIdx.x;
  for (int i = t; i < 1024; i += 256) g[i] = GT2[b*1024 + i];
  __syncthreads();
  const int c = blockIdx.y*256 + t;
  const float* kr = k_w + (size_t)c*512;
  const float* vr = v_w + (size_t)c*512;
  float k0a=0.f,k1a=0.f,v0a=0.f,v1a=0.f;
  for (int d = 0; d < 512; d += 8){
    F8 kw = load8f(kr + d); F8 vw = load8f(vr + d);
    #pragma unroll
    for (int i = 0; i < 8; ++i){
      float g0 = g[(d+i)*2], g1 = g[(d+i)*2+1];
      k0a += kw.v[i]*g0; k1a += kw.v[i]*g1;
      v0a += vw.v[i]*g0; v1a += vw.v[i]*g1;
    }
  }
  DK[b*512 + c]  = k0a - k1a;
  DV[b*512 + c]  = v0a - v1a;
  V1L[b*512 + c] = v1a + v_b[c];
}

// ============ k0 phase E: wdiff + beta4 -> PRE ==============================
// grid (16,2), block 256: thread = column i = by*256+tid
__global__ __launch_bounds__(256) void k0e_qpre(
    const float* __restrict__ DK,
    const float* __restrict__ q_w, const float* __restrict__ q_b,
    float* __restrict__ PRE)
{
  __shared__ float dkl[512];
  const int b = blockIdx.x;
  const int t = threadIdx.x;
  for (int i = t; i < 512; i += 256) dkl[i] = DK[b*512 + i];
  __syncthreads();
  const int i = blockIdx.y*256 + t;
  float w0=0.f,w1=0.f,w2=0.f,w3=0.f;
  for (int c = 0; c < 512; c += 4){
    w0 += dkl[c]  *q_w[(size_t)(c)  *512 + i];
    w1 += dkl[c+1]*q_w[(size_t)(c+1)*512 + i];
    w2 += dkl[c+2]*q_w[(size_t)(c+2)*512 + i];
    w3 += dkl[c+3]*q_w[(size_t)(c+3)*512 + i];
  }
  float* P = PRE + (size_t)b * PRE_STRIDE;
  P[0*512+i]=w0; P[1*512+i]=w1; P[2*512+i]=w2; P[3*512+i]=w3;
  if (blockIdx.y == 0 && t < 4){
    float bsum = 0.f;
    for (int c = t; c < 512; c += 4) bsum += dkl[c]*q_b[c];
    P[2048 + t] = bsum;
  }
}

// ============ k0 phase F: base + M -> PRE ===================================
// grid (16,2), block 256: thread = row r = by*256+tid
__global__ __launch_bounds__(256) void k0f_mpre(
    const float* __restrict__ DV, const float* __restrict__ V1L,
    const float* __restrict__ merge_w, const float* __restrict__ merge_b,
    float* __restrict__ PRE)
{
  __shared__ float dvl[512], v1ll[512];
  const int b = blockIdx.x;
  const int t = threadIdx.x;
  for (int i = t; i < 512; i += 256){
    dvl[i] = DV[b*512 + i]; v1ll[i] = V1L[b*512 + i];
  }
  __syncthreads();
  const int r = blockIdx.y*256 + t;
  const float* mw = merge_w + (size_t)r*512;
  float ab = merge_b[r];
  float mh[4] = {0.f,0.f,0.f,0.f};
  for (int c = 0; c < 512; c += 8){
    F8 w = load8f(mw + c);
    #pragma unroll
    for (int i = 0; i < 8; ++i){
      ab += w.v[i]*v1ll[c+i];
      mh[i&3] += w.v[i]*dvl[c+i];
    }
  }
  float* P = PRE + (size_t)b * PRE_STRIDE;
  P[2064 + r] = ab;
  *(float4*)&P[2576 + r*4] = make_float4(mh[0],mh[1],mh[2],mh[3]);
}

// ---------------- convert fp32 -> bf16 (flat) ------------------------------
__global__ __launch_bounds__(256) void kcvt(const float* __restrict__ s,
                                            u16* __restrict__ d, int n8)
{
  int g = blockIdx.x*256 + threadIdx.x;
  if (g >= n8) return;
  F8 v = load8f(s + (size_t)g*8);
  u16 o[8];
  #pragma unroll
  for (int i=0;i<8;++i) o[i] = f2bf(v.v[i]);
  *(uint4*)(d + (size_t)g*8) = *(uint4*)o;
}

// ---- K1: single pass over x: emit x-bf16 rows + attn+merge+LN(n0) y rows --
__global__ __launch_bounds__(256) void k1_fused(
    const float* __restrict__ x, const float* __restrict__ PRE,
    const float* __restrict__ n0_g, const float* __restrict__ n0_b,
    int j0_global, int cstride, u16* __restrict__ XYb)
{
  __shared__ float wd[4][512];
  __shared__ float bs[512];
  __shared__ float Mm[512][4];
  __shared__ float gam[512], bet[512];
  __shared__ float beta4[4];
  const int tid = threadIdx.x;
  const int jl = blockIdx.x*256 + tid;
  const int jg = j0_global + jl;
  const int b = jg >> 12, n = jg & 4095;
  const float* P = PRE + (size_t)b * PRE_STRIDE;
  for (int i = tid; i < 2048; i += 256) wd[i>>9][i&511] = P[i];
  if (tid < 4) beta4[tid] = P[2048 + tid];
  for (int i = tid; i < 512; i += 256){
    bs[i] = P[2064 + i]; gam[i] = n0_g[i]; bet[i] = n0_b[i];
  }
  for (int i = tid; i < 2048; i += 256) Mm[i>>2][i&3] = P[2576 + i];
  __syncthreads();
  const float* xc = x + (size_t)b*2097152 + n;
  float l0=beta4[0], l1=beta4[1], l2=beta4[2], l3=beta4[3];
  for (int i = 0; i < 512; ++i){
    float xv = xc[(size_t)i*4096];
    XYb[(size_t)i*cstride + jl] = f2bf(xv);      // x -> bf16 row i
    l0 += wd[0][i]*xv; l1 += wd[1][i]*xv; l2 += wd[2][i]*xv; l3 += wd[3][i]*xv;
  }
  const float sc = 0.0883883476483184405f;
  float p0 = 1.f/(1.f+expf(-sc*l0));
  float p1 = 1.f/(1.f+expf(-sc*l1));
  float p2 = 1.f/(1.f+expf(-sc*l2));
  float p3 = 1.f/(1.f+expf(-sc*l3));
  float s=0.f, s2=0.f;
  for (int c = 0; c < 512; ++c){
    float m = bs[c] + Mm[c][0]*p0 + Mm[c][1]*p1 + Mm[c][2]*p2 + Mm[c][3]*p3;
    s += m; s2 += m*m;
  }
  float mean = s*(1.f/512.f);
  float rs = rsqrtf(s2*(1.f/512.f) - mean*mean + 1e-5f);
  for (int c = 0; c < 512; ++c){
    float m = bs[c] + Mm[c][0]*p0 + Mm[c][1]*p1 + Mm[c][2]*p2 + Mm[c][3]*p3;
    XYb[(size_t)(512+c)*cstride + jl] = f2bf((m - mean)*rs*gam[c] + bet[c]);
  }
}

// ---------------- MFMA GEMM 128x128 tile (m1, m2) --------------------------
__global__ __launch_bounds__(256) void mfma_gemm(
    const u16* __restrict__ Wb, const float* __restrict__ bias,
    const u16* __restrict__ Xb, int K, int C,
    float* __restrict__ OutF, u16* __restrict__ OutH, int do_gelu)
{
  __shared__ __align__(16) u16 Asl[128*32];
  __shared__ __align__(16) u16 Bsl[128*32];
  const int tid = threadIdx.x;
  const int lane = tid & 63, w = tid >> 6;
  const int bj = blockIdx.x, bi = blockIdx.y;
  const int roff = (w >> 1) * 64;
  const int noff = (w & 1) * 64;
  const int lm = lane & 15, quad = lane >> 4;

  f32x4 acc[4][4];
  #pragma unroll
  for (int i=0;i<4;++i){
    #pragma unroll
    for (int j=0;j<4;++j) acc[i][j] = (f32x4){0.f,0.f,0.f,0.f};
  }
  const int ar = tid >> 1;
  const int akc = (tid & 1) * 16;
  const u16* aG = Wb + (size_t)(bi*128 + ar)*K + akc;
  const int jg = tid & 15;
  const int kp = tid >> 4;
  const u16* bG = Xb + (size_t)(2*kp)*C + (size_t)bj*128 + (size_t)jg*8;

  for (int k0 = 0; k0 < K; k0 += 32){
    uint4 a0 = *(const uint4*)(aG + k0);
    uint4 a1 = *(const uint4*)(aG + k0 + 8);
    uint4 r0 = *(const uint4*)(bG + (size_t)k0*C);
    uint4 r1 = *(const uint4*)(bG + (size_t)(k0+1)*C);
    *(uint4*)&Asl[ar*32 + akc]     = a0;
    *(uint4*)&Asl[ar*32 + akc + 8] = a1;
    const u16* s0 = (const u16*)&r0;
    const u16* s1 = (const u16*)&r1;
    #pragma unroll
    for (int jj = 0; jj < 8; ++jj){
      unsigned int dw = (unsigned int)s0[jj] | ((unsigned int)s1[jj] << 16);
      *(unsigned int*)&Bsl[(jg*8 + jj)*32 + 2*kp] = dw;
    }
    __syncthreads();
    bfrag av[4], bv[4];
    #pragma unroll
    for (int i=0;i<4;++i)
      av[i] = *(const bfrag*)&Asl[(roff + 16*i + lm)*32 + quad*8];
    #pragma unroll
    for (int j=0;j<4;++j)
      bv[j] = *(const bfrag*)&Bsl[(noff + 16*j + lm)*32 + quad*8];
    #pragma unroll
    for (int i=0;i<4;++i){
      #pragma unroll
      for (int j=0;j<4;++j)
        acc[i][j] = __builtin_amdgcn_mfma_f32_16x16x32_bf16(av[i], bv[j], acc[i][j], 0,0,0);
    }
    __syncthreads();
  }
  const size_t colBase = (size_t)bj*128 + noff + lm;
  #pragma unroll
  for (int i=0;i<4;++i){
    int Rb = bi*128 + roff + 16*i + quad*4;
    #pragma unroll
    for (int r=0;r<4;++r){
      int R = Rb + r;
      float bb = bias[R];
      #pragma unroll
      for (int j=0;j<4;++j){
        float v = acc[i][j][r] + bb;
        if (do_gelu) v = gelu_f(v);
        if (OutH) OutH[(size_t)R*C + colBase + 16*j] = f2bf(v);
        else      OutF[(size_t)R*C + colBase + 16*j] = v;
      }
    }
  }
}

// ---------------- MFMA GEMM 64-row x 256-col tile (g1) ---------------------
// Wg: bf16 [64][K]; Xb: bf16 [K][C]; Out fp32 [64][C]. K=512.
__global__ __launch_bounds__(256) void mfma_gemm_m64(
    const u16* __restrict__ Wg, const float* __restrict__ bias,
    const u16* __restrict__ Xb, int K, int C,
    float* __restrict__ Out)
{
  __shared__ __align__(16) u16 Asl[64*32];
  __shared__ __align__(16) u16 Bsl[256*32];
  const int tid = threadIdx.x;
  const int lane = tid & 63, w = tid >> 6;
  const int bj = blockIdx.x;
  const int woff = w * 64;                    // wave's column offset
  const int lm = lane & 15, quad = lane >> 4;

  f32x4 acc[4][4];
  #pragma unroll
  for (int i=0;i<4;++i){
    #pragma unroll
    for (int j=0;j<4;++j) acc[i][j] = (f32x4){0.f,0.f,0.f,0.f};
  }
  const int ar = tid >> 2;                    // 0..63 rows
  const int akc = (tid & 3) * 8;              // k offset
  const u16* aG = Wg + (size_t)ar*K + akc;
  const int jg = tid & 31;                    // col group (8 cols), 256 cols
  const int kp8 = tid >> 5;                   // 0..7
  const u16* bG = Xb + (size_t)bj*256 + (size_t)jg*8;

  for (int k0 = 0; k0 < K; k0 += 32){
    uint4 a0 = *(const uint4*)(aG + k0);
    *(uint4*)&Asl[ar*32 + akc] = a0;
    #pragma unroll
    for (int s = 0; s < 2; ++s){
      int kp = kp8 + s*8;                     // pairs 0..15
      uint4 r0 = *(const uint4*)(bG + (size_t)(k0 + 2*kp)*C);
      uint4 r1 = *(const uint4*)(bG + (size_t)(k0 + 2*kp + 1)*C);
      const u16* s0 = (const u16*)&r0;
      const u16* s1 = (const u16*)&r1;
      #pragma unroll
      for (int jj = 0; jj < 8; ++jj){
        unsigned int dw = (unsigned int)s0[jj] | ((unsigned int)s1[jj] << 16);
        *(unsigned int*)&Bsl[(jg*8 + jj)*32 + 2*kp] = dw;
      }
    }
    __syncthreads();
    bfrag av[4], bv[4];
    #pragma unroll
    for (int i=0;i<4;++i)
      av[i] = *(const bfrag*)&Asl[(16*i + lm)*32 + quad*8];
    #pragma unroll
    for (int j=0;j<4;++j)
      bv[j] = *(const bfrag*)&Bsl[(woff + 16*j + lm)*32 + quad*8];
    #pragma unroll
    for (int i=0;i<4;++i){
      #pragma unroll
      for (int j=0;j<4;++j)
        acc[i][j] = __builtin_amdgcn_mfma_f32_16x16x32_bf16(av[i], bv[j], acc[i][j], 0,0,0);
    }
    __syncthreads();
  }
  const size_t colBase = (size_t)bj*256 + woff + lm;
  #pragma unroll
  for (int i=0;i<4;++i){
    int Rb = 16*i + quad*4;
    #pragma unroll
    for (int r=0;r<4;++r){
      int R = Rb + r;
      float bb = bias[R];
      #pragma unroll
      for (int j=0;j<4;++j)
        Out[(size_t)R*C + colBase + 16*j] = acc[i][j][r] + bb;
    }
  }
}

// ------------- LN over 512 channels + x residual -> bf16 -------------------
__global__ __launch_bounds__(256) void k_ln512res(
    const float* __restrict__ In, int cstride,
    const float* __restrict__ gamma, const float* __restrict__ beta,
    const float* __restrict__ Xres, int j0_global,
    u16* __restrict__ Out)
{
  __shared__ float gam[512], bet[512];
  const int tid = threadIdx.x;
  for (int c = tid; c < 512; c += 256){ gam[c]=gamma[c]; bet[c]=beta[c]; }
  __syncthreads();
  const int jl = blockIdx.x*256 + tid;
  float s=0.f, s2=0.f;
  for (int c = 0; c < 512; ++c){
    float v = In[(size_t)c*cstride + jl];
    s += v; s2 += v*v;
  }
  float m = s*(1.f/512.f);
  float rs = rsqrtf(s2*(1.f/512.f) - m*m + 1e-5f);
  const int jg = j0_global + jl;
  const size_t xbase = (size_t)(jg>>12)*2097152 + (size_t)(jg&4095);
  for (int c = 0; c < 512; ++c){
    float v = In[(size_t)c*cstride + jl];
    Out[(size_t)c*cstride + jl] =
        f2bf((v - m)*rs*gam[c] + bet[c] + Xres[xbase + (size_t)c*4096]);
  }
}

// ---------------- head: LN64+gelu -> 16 -> 4 -> 2, softmax ch0 -------------
__global__ __launch_bounds__(256) void k_head(
    const float* __restrict__ G, int cstride,
    const float* __restrict__ gl1_g, const float* __restrict__ gl1_b,
    const float* __restrict__ g2_w, const float* __restrict__ g2_b,
    const float* __restrict__ gl2_g, const float* __restrict__ gl2_b,
    const float* __restrict__ g3_w, const float* __restrict__ g3_b,
    const float* __restrict__ gl3_g, const float* __restrict__ gl3_b,
    const float* __restrict__ g4_w, const float* __restrict__ g4_b, int has_g4b,
    float* __restrict__ Outp, int j0_global)
{
  __shared__ float L1g[64], L1b[64];
  __shared__ float W2[16][64], B2v[16], G2v[16], T2v[16];
  __shared__ float W3[4][16], B3v[4], G3v[4], T3v[4];
  __shared__ float W4d[4]; __shared__ float b4d;
  const int tid = threadIdx.x;
  if (tid < 64){ L1g[tid]=gl1_g[tid]; L1b[tid]=gl1_b[tid]; }
  for (int i = tid; i < 1024; i += 256) W2[i>>6][i&63] = g2_w[i];
  if (tid < 16){ B2v[tid]=g2_b[tid]; G2v[tid]=gl2_g[tid]; T2v[tid]=gl2_b[tid]; }
  if (tid < 64) W3[tid>>4][tid&15] = g3_w[tid];
  if (tid < 4){ B3v[tid]=g3_b[tid]; G3v[tid]=gl3_g[tid]; T3v[tid]=gl3_b[tid];
                W4d[tid] = g4_w[tid] - g4_w[4+tid]; }
  if (tid == 0) b4d = has_g4b ? (g4_b[0] - g4_b[1]) : 0.f;
  __syncthreads();
  const int jl = blockIdx.x*256 + tid;
  float a1[64]; float s=0.f;
  #pragma unroll
  for (int c=0;c<64;++c){ a1[c] = G[(size_t)c*cstride + jl]; s += a1[c]; }
  float m = s*(1.f/64.f); float s2=0.f;
  #pragma unroll
  for (int c=0;c<64;++c){ float d=a1[c]-m; s2+=d*d; }
  float rs = rsqrtf(s2*(1.f/64.f)+1e-5f);
  #pragma unroll
  for (int c=0;c<64;++c) a1[c] = gelu_f((a1[c]-m)*rs*L1g[c]+L1b[c]);

  float a2[16]; s=0.f;
  #pragma unroll
  for (int i=0;i<16;++i){
    float acc = B2v[i];
    #pragma unroll
    for (int o=0;o<64;++o) acc += W2[i][o]*a1[o];
    a2[i]=acc; s+=acc;
  }
  m = s*(1.f/16.f); s2=0.f;
  #pragma unroll
  for (int i=0;i<16;++i){ float d=a2[i]-m; s2+=d*d; }
  rs = rsqrtf(s2*(1.f/16.f)+1e-5f);
  float a2g[16];
  #pragma unroll
  for (int i=0;i<16;++i) a2g[i] = gelu_f((a2[i]-m)*rs*G2v[i]+T2v[i]);

  float a3[4]; s=0.f;
  #pragma unroll
  for (int i=0;i<4;++i){
    float acc=B3v[i];
    #pragma unroll
    for (int o=0;o<16;++o) acc += W3[i][o]*a2g[o];
    a3[i]=acc; s+=acc;
  }
  m = s*0.25f; s2=0.f;
  #pragma unroll
  for (int i=0;i<4;++i){ float d=a3[i]-m; s2+=d*d; }
  rs = rsqrtf(s2*0.25f+1e-5f);
  float z = b4d;
  #pragma unroll
  for (int i=0;i<4;++i) z += W4d[i]*gelu_f((a3[i]-m)*rs*G3v[i]+T3v[i]);
  Outp[j0_global + jl] = 1.f/(1.f+expf(-z));
}

extern "C" void kernel_launch(void* const* d_in, const int* in_sizes, int n_in,
                              void* d_out, int out_size, void* d_ws, size_t ws_size,
                              hipStream_t stream)
{
  const float* gtok  = (const float*)d_in[0];
  const float* x     = (const float*)d_in[1];
  const float* ws1_w = (const float*)d_in[2];
  const float* ws1_b = (const float*)d_in[3];
  const float* ws2_w = (const float*)d_in[4];
  const float* ws2_b = (const float*)d_in[5];
  const float* wc1_w = (const float*)d_in[6];
  const float* wc1_b = (const float*)d_in[7];
  const float* wc2_w = (const float*)d_in[8];
  const float* wc2_b = (const float*)d_in[9];
  const float* q_w   = (const float*)d_in[10];
  const float* q_b   = (const float*)d_in[11];
  const float* k_w   = (const float*)d_in[12];
  const float* v_w   = (const float*)d_in[14];
  const float* v_b   = (const float*)d_in[15];
  const float* merge_w = (const float*)d_in[16];
  const float* merge_b = (const float*)d_in[17];
  const float* m1_w  = (const float*)d_in[18];
  const float* m1_b  = (const float*)d_in[19];
  const float* m2_w  = (const float*)d_in[20];
  const float* m2_b  = (const float*)d_in[21];
  const float* n0_g  = (const float*)d_in[22];
  const float* n0_b  = (const float*)d_in[23];
  const float* n1_g  = (const float*)d_in[24];
  const float* n1_b  = (const float*)d_in[25];
  const float* g1_w  = (const float*)d_in[26];
  const float* g1_b  = (const float*)d_in[27];
  const float* gl1_g = (const float*)d_in[28];
  const float* gl1_b = (const float*)d_in[29];
  const float* g2_w  = (const float*)d_in[30];
  const float* g2_b  = (const float*)d_in[31];
  const float* gl2_g = (const float*)d_in[32];
  const float* gl2_b = (const float*)d_in[33];
  const float* g3_w  = (const float*)d_in[34];
  const float* g3_b  = (const float*)d_in[35];
  const float* gl3_g = (const float*)d_in[36];
  const float* gl3_b = (const float*)d_in[37];
  const float* g4_w  = (const float*)d_in[38];
  const float* g4_b  = (n_in > 39) ? (const float*)d_in[39] : nullptr;

  const int TOT = 65536;
  const size_t PRE_BYTES = (size_t)16 * PRE_STRIDE * 4;   // 295,936
  // fixed scratch layout (256-B aligned sizes)
  const size_t GT1_B = 65536, HID_B = 262144, GT2_B = 65536;
  const size_t DK_B = 32768, DV_B = 32768, V1L_B = 32768;
  const size_t WB1_B = (size_t)1024*1024*2;
  const size_t WB2_B = (size_t)512*1024*2;
  const size_t WG1_B = (size_t)64*512*2;
  const size_t FIXED = PRE_BYTES + GT1_B + HID_B + GT2_B + DK_B + DV_B + V1L_B
                     + WB1_B + WB2_B + WG1_B;
  // per-chunk: R1 2048C + R2 2048C + bufG 256C bytes
  int C = 65536;
  while (C > 4096 && FIXED + (size_t)4352*C > ws_size) C >>= 1;
  const int nch = TOT / C;

  char* wsb = (char*)d_ws;
  size_t off = 0;
  float* PRE = (float*)(wsb + off); off += PRE_BYTES;
  float* GT1 = (float*)(wsb + off); off += GT1_B;
  float* HID = (float*)(wsb + off); off += HID_B;
  float* GT2 = (float*)(wsb + off); off += GT2_B;
  float* DK  = (float*)(wsb + off); off += DK_B;
  float* DV  = (float*)(wsb + off); off += DV_B;
  float* V1L = (float*)(wsb + off); off += V1L_B;
  u16* Wb1   = (u16*)(wsb + off);   off += WB1_B;
  u16* Wb2   = (u16*)(wsb + off);   off += WB2_B;
  u16* Wg1   = (u16*)(wsb + off);   off += WG1_B;
  char* R1 = wsb + off; off += (size_t)2048*C;
  char* R2 = wsb + off; off += (size_t)2048*C;
  float* bufG = (float*)(wsb + off); off += (size_t)256*C;

  dim3 blk(256);
  // weight conversions
  hipLaunchKernelGGL(kcvt, dim3(512), blk, 0, stream, m1_w, Wb1, 1024*1024/8);
  hipLaunchKernelGGL(kcvt, dim3(256), blk, 0, stream, m2_w, Wb2, 512*1024/8);
  hipLaunchKernelGGL(kcvt, dim3(16),  blk, 0, stream, g1_w, Wg1, 64*512/8);
  // k0 phases (parallelized precompute)
  hipLaunchKernelGGL(k0a_mlps, dim3(16,2), blk, 0, stream,
      gtok, ws1_w, ws1_b, ws2_w, ws2_b, GT1);
  hipLaunchKernelGGL(k0b_fc1, dim3(16,8), blk, 0, stream, GT1, wc1_w, wc1_b, HID);
  hipLaunchKernelGGL(k0c_fc2, dim3(16,2), blk, 0, stream, GT1, HID, wc2_w, wc2_b, GT2);
  hipLaunchKernelGGL(k0d_kv,  dim3(16,2), blk, 0, stream, GT2, k_w, v_w, v_b, DK, DV, V1L);
  hipLaunchKernelGGL(k0e_qpre, dim3(16,2), blk, 0, stream, DK, q_w, q_b, PRE);
  hipLaunchKernelGGL(k0f_mpre, dim3(16,2), blk, 0, stream, DV, V1L, merge_w, merge_b, PRE);

  for (int ch = 0; ch < nch; ++ch){
    const int j0 = ch * C;
    u16* XYb = (u16*)R1;            // [1024][C] bf16 (x rows 0-511, y rows 512+)
    u16* T1b = (u16*)R2;            // [1024][C] bf16
    float* t2 = (float*)R1;         // [512][C] fp32 (aliases XYb after m1)
    u16* XDb  = (u16*)R2;           // [512][C] bf16 (aliases T1b after m2)
    dim3 cols(C/256);
    // x->bf16 + attn + merge + LN(n0) in one pass over x
    hipLaunchKernelGGL(k1_fused, cols, blk, 0, stream,
        x, PRE, n0_g, n0_b, j0, C, XYb);
    // t1 = gelu(m1 @ XYb + b) -> T1b
    hipLaunchKernelGGL(mfma_gemm, dim3(C/128, 8), blk, 0, stream,
        Wb1, m1_b, XYb, 1024, C, (float*)nullptr, T1b, 1);
    // t2 = m2 @ t1 + b -> fp32
    hipLaunchKernelGGL(mfma_gemm, dim3(C/128, 4), blk, 0, stream,
        Wb2, m2_b, T1b, 1024, C, t2, (u16*)nullptr, 0);
    // xd = x + LN_c(t2; n1) -> bf16
    hipLaunchKernelGGL(k_ln512res, cols, blk, 0, stream,
        t2, C, n1_g, n1_b, x, j0, XDb);
    // g1raw = g1_w @ xd + b (MFMA, 64-row tile)
    hipLaunchKernelGGL(mfma_gemm_m64, dim3(C/256), blk, 0, stream,
        Wg1, g1_b, XDb, 512, C, bufG);
    // head
    hipLaunchKernelGGL(k_head, cols, blk, 0, stream,
        bufG, C, gl1_g, gl1_b, g2_w, g2_b, gl2_g, gl2_b,
        g3_w, g3_b, gl3_g, gl3_b,
        g4_w, g4_b ? g4_b : g4_w, g4_b ? 1 : 0, (float*)d_out, j0);
  }
}

// Round 5
// 1299.525 us; speedup vs baseline: 3.2661x; 1.0836x over previous
//
#include <hip/hip_runtime.h>
#include <math.h>

typedef unsigned short u16;
typedef __attribute__((ext_vector_type(8))) short bfrag;   // 8 bf16 (4 VGPRs)
typedef __attribute__((ext_vector_type(4))) float f32x4;

__device__ __forceinline__ float gelu_f(float x){
  return 0.5f * x * (1.0f + erff(x * 0.70710678118654752440f));
}
__device__ __forceinline__ u16 f2bf(float f){
  union { float f; unsigned int i; } c; c.f = f;
  unsigned int i = c.i;
  return (u16)((i + 0x7FFFu + ((i >> 16) & 1u)) >> 16);
}

struct F8 { float v[8]; };
__device__ __forceinline__ F8 load8f(const float* p){
  float4 a = *(const float4*)p; float4 b = *(const float4*)(p + 4);
  F8 r; r.v[0]=a.x; r.v[1]=a.y; r.v[2]=a.z; r.v[3]=a.w;
  r.v[4]=b.x; r.v[5]=b.y; r.v[6]=b.z; r.v[7]=b.w; return r;
}

// async global->LDS, 16B per lane; LDS dest = wave-uniform base + lane*16
__device__ __forceinline__ void async16(const void* g, void* l){
  __builtin_amdgcn_global_load_lds(
      (const __attribute__((address_space(1))) unsigned int*)g,
      (__attribute__((address_space(3))) unsigned int*)l, 16, 0, 0);
}

// PRE layout per batch (stride 4624 floats):
//   [0..2047] wdiff[h][i] | [2048..2051] beta[h] | [2064..2575] base[r]
//   [2576..4623] M[r][h] (r*4+h)
#define PRE_STRIDE 4624

// ============ k0 phase A: mlp_s (2->256->2) + residual -> GT1 ==============
__global__ __launch_bounds__(256) void k0a_mlps(
    const float* __restrict__ gtok,
    const float* __restrict__ ws1_w, const float* __restrict__ ws1_b,
    const float* __restrict__ ws2_w, const float* __restrict__ ws2_b,
    float* __restrict__ GT1)
{
  __shared__ float sw1[256][2]; __shared__ float sb1[256];
  __shared__ float sw2[2][256];
  const int b = blockIdx.x;
  const int t = threadIdx.x;
  sw1[t][0] = ws1_w[2*t]; sw1[t][1] = ws1_w[2*t+1];
  sb1[t] = ws1_b[t];
  sw2[0][t] = ws2_w[t]; sw2[1][t] = ws2_w[256+t];
  __syncthreads();
  const int j = blockIdx.y*256 + t;
  const float a0 = gtok[b*1024 + 2*j], a1 = gtok[b*1024 + 2*j + 1];
  float s0 = ws2_b[0], s1 = ws2_b[1];
  #pragma unroll 4
  for (int o = 0; o < 256; ++o){
    float h = gelu_f(sw1[o][0]*a0 + sw1[o][1]*a1 + sb1[o]);
    s0 += sw2[0][o]*h; s1 += sw2[1][o]*h;
  }
  GT1[b*1024 + 2*j]     = a0 + s0;
  GT1[b*1024 + 2*j + 1] = a1 + s1;
}

// ============ k0 phase B: fc1 of mlp_c (512->2048) -> HID ==================
__global__ __launch_bounds__(256) void k0b_fc1(
    const float* __restrict__ GT1,
    const float* __restrict__ wc1_w, const float* __restrict__ wc1_b,
    float* __restrict__ HID)
{
  __shared__ float g[1024];
  const int b = blockIdx.x;
  const int t = threadIdx.x;
  for (int i = t; i < 1024; i += 256) g[i] = GT1[b*1024 + i];
  __syncthreads();
  const int o = blockIdx.y*256 + t;
  const float* wr = wc1_w + (size_t)o*512;
  float acc0 = wc1_b[o], acc1 = acc0;
  for (int d = 0; d < 512; d += 8){
    F8 w = load8f(wr + d);
    #pragma unroll
    for (int i = 0; i < 8; ++i){
      acc0 += w.v[i]*g[(d+i)*2];
      acc1 += w.v[i]*g[(d+i)*2+1];
    }
  }
  HID[b*4096 + o]        = gelu_f(acc0);
  HID[b*4096 + 2048 + o] = gelu_f(acc1);
}

// ============ k0 phase C: fc2 of mlp_c (2048->512) + residual -> GT2 =======
__global__ __launch_bounds__(256) void k0c_fc2(
    const float* __restrict__ GT1, const float* __restrict__ HID,
    const float* __restrict__ wc2_w, const float* __restrict__ wc2_b,
    float* __restrict__ GT2)
{
  __shared__ float h0[2048], h1[2048];
  const int b = blockIdx.x;
  const int t = threadIdx.x;
  for (int i = t; i < 2048; i += 256){
    h0[i] = HID[b*4096 + i]; h1[i] = HID[b*4096 + 2048 + i];
  }
  __syncthreads();
  const int d = blockIdx.y*256 + t;
  const float* wr = wc2_w + (size_t)d*2048;
  float acc0 = wc2_b[d], acc1 = acc0;
  for (int o = 0; o < 2048; o += 8){
    F8 w = load8f(wr + o);
    #pragma unroll
    for (int i = 0; i < 8; ++i){
      acc0 += w.v[i]*h0[o+i];
      acc1 += w.v[i]*h1[o+i];
    }
  }
  GT2[b*1024 + 2*d]     = GT1[b*1024 + 2*d]     + acc0;
  GT2[b*1024 + 2*d + 1] = GT1[b*1024 + 2*d + 1] + acc1;
}

// ============ k0 phase D: k,v -> dk, dv, v1l ================================
__global__ __launch_bounds__(256) void k0d_kv(
    const float* __restrict__ GT2,
    const float* __restrict__ k_w,
    const float* __restrict__ v_w, const float* __restrict__ v_b,
    float* __restrict__ DK, float* __restrict__ DV, float* __restrict__ V1L)
{
  __shared__ float g[1024];
  const int b = blockIdx.x;
  const int t = threadIdx.x;
  for (int i = t; i < 1024; i += 256) g[i] = GT2[b*1024 + i];
  __syncthreads();
  const int c = blockIdx.y*256 + t;
  const float* kr = k_w + (size_t)c*512;
  const float* vr = v_w + (size_t)c*512;
  float k0a=0.f,k1a=0.f,v0a=0.f,v1a=0.f;
  for (int d = 0; d < 512; d += 8){
    F8 kw = load8f(kr + d); F8 vw = load8f(vr + d);
    #pragma unroll
    for (int i = 0; i < 8; ++i){
      float g0 = g[(d+i)*2], g1 = g[(d+i)*2+1];
      k0a += kw.v[i]*g0; k1a += kw.v[i]*g1;
      v0a += vw.v[i]*g0; v1a += vw.v[i]*g1;
    }
  }
  DK[b*512 + c]  = k0a - k1a;
  DV[b*512 + c]  = v0a - v1a;
  V1L[b*512 + c] = v1a + v_b[c];
}

// ============ k0 phase E: wdiff + beta4 -> PRE ==============================
__global__ __launch_bounds__(256) void k0e_qpre(
    const float* __restrict__ DK,
    const float* __restrict__ q_w, const float* __restrict__ q_b,
    float* __restrict__ PRE)
{
  __shared__ float dkl[512];
  const int b = blockIdx.x;
  const int t = threadIdx.x;
  for (int i = t; i < 512; i += 256) dkl[i] = DK[b*512 + i];
  __syncthreads();
  const int i = blockIdx.y*256 + t;
  float w0=0.f,w1=0.f,w2=0.f,w3=0.f;
  for (int c = 0; c < 512; c += 4){
    w0 += dkl[c]  *q_w[(size_t)(c)  *512 + i];
    w1 += dkl[c+1]*q_w[(size_t)(c+1)*512 + i];
    w2 += dkl[c+2]*q_w[(size_t)(c+2)*512 + i];
    w3 += dkl[c+3]*q_w[(size_t)(c+3)*512 + i];
  }
  float* P = PRE + (size_t)b * PRE_STRIDE;
  P[0*512+i]=w0; P[1*512+i]=w1; P[2*512+i]=w2; P[3*512+i]=w3;
  if (blockIdx.y == 0 && t < 4){
    float bsum = 0.f;
    for (int c = t; c < 512; c += 4) bsum += dkl[c]*q_b[c];
    P[2048 + t] = bsum;
  }
}

// ============ k0 phase F: base + M -> PRE ===================================
__global__ __launch_bounds__(256) void k0f_mpre(
    const float* __restrict__ DV, const float* __restrict__ V1L,
    const float* __restrict__ merge_w, const float* __restrict__ merge_b,
    float* __restrict__ PRE)
{
  __shared__ float dvl[512], v1ll[512];
  const int b = blockIdx.x;
  const int t = threadIdx.x;
  for (int i = t; i < 512; i += 256){
    dvl[i] = DV[b*512 + i]; v1ll[i] = V1L[b*512 + i];
  }
  __syncthreads();
  const int r = blockIdx.y*256 + t;
  const float* mw = merge_w + (size_t)r*512;
  float ab = merge_b[r];
  float mh[4] = {0.f,0.f,0.f,0.f};
  for (int c = 0; c < 512; c += 8){
    F8 w = load8f(mw + c);
    #pragma unroll
    for (int i = 0; i < 8; ++i){
      ab += w.v[i]*v1ll[c+i];
      mh[i&3] += w.v[i]*dvl[c+i];
    }
  }
  float* P = PRE + (size_t)b * PRE_STRIDE;
  P[2064 + r] = ab;
  *(float4*)&P[2576 + r*4] = make_float4(mh[0],mh[1],mh[2],mh[3]);
}

// ---------------- convert fp32 -> bf16 (flat) ------------------------------
__global__ __launch_bounds__(256) void kcvt(const float* __restrict__ s,
                                            u16* __restrict__ d, int n8)
{
  int g = blockIdx.x*256 + threadIdx.x;
  if (g >= n8) return;
  F8 v = load8f(s + (size_t)g*8);
  u16 o[8];
  #pragma unroll
  for (int i=0;i<8;++i) o[i] = f2bf(v.v[i]);
  *(uint4*)(d + (size_t)g*8) = *(uint4*)o;
}

// ------- build Wg64 [64][1024] = [g1_w | g1_w] bf16 ------------------------
__global__ __launch_bounds__(256) void kcvt_dup(const float* __restrict__ g1w,
                                                u16* __restrict__ out)
{
  int idx = blockIdx.x*256 + threadIdx.x;      // 65536 total
  int r = idx >> 10, k = idx & 1023;
  out[idx] = f2bf(g1w[r*512 + (k & 511)]);
}

// ---- K1: one pass over x: XYbT[j][0..511]=x bf16, [512..1023]=attn+LN(n0) --
__global__ __launch_bounds__(256) void k1_fused(
    const float* __restrict__ x, const float* __restrict__ PRE,
    const float* __restrict__ n0_g, const float* __restrict__ n0_b,
    int j0_global, u16* __restrict__ XYbT)
{
  __shared__ float wd[4][512];
  __shared__ float bs[512];
  __shared__ float Mm[512][4];
  __shared__ float gam[512], bet[512];
  __shared__ float beta4[4];
  const int tid = threadIdx.x;
  const int jl = blockIdx.x*256 + tid;
  const int jg = j0_global + jl;
  const int b = jg >> 12, n = jg & 4095;
  const float* P = PRE + (size_t)b * PRE_STRIDE;
  for (int i = tid; i < 2048; i += 256) wd[i>>9][i&511] = P[i];
  if (tid < 4) beta4[tid] = P[2048 + tid];
  for (int i = tid; i < 512; i += 256){
    bs[i] = P[2064 + i]; gam[i] = n0_g[i]; bet[i] = n0_b[i];
  }
  for (int i = tid; i < 2048; i += 256) Mm[i>>2][i&3] = P[2576 + i];
  __syncthreads();
  const float* xc = x + (size_t)b*2097152 + n;
  u16* col = XYbT + (size_t)jl*1024;
  float l0=beta4[0], l1=beta4[1], l2=beta4[2], l3=beta4[3];
  for (int i0 = 0; i0 < 512; i0 += 8){
    u16 ob[8];
    #pragma unroll
    for (int m = 0; m < 8; ++m){
      float xv = xc[(size_t)(i0+m)*4096];
      ob[m] = f2bf(xv);
      l0 += wd[0][i0+m]*xv; l1 += wd[1][i0+m]*xv;
      l2 += wd[2][i0+m]*xv; l3 += wd[3][i0+m]*xv;
    }
    *(uint4*)&col[i0] = *(uint4*)ob;
  }
  const float sc = 0.0883883476483184405f;
  float p0 = 1.f/(1.f+expf(-sc*l0));
  float p1 = 1.f/(1.f+expf(-sc*l1));
  float p2 = 1.f/(1.f+expf(-sc*l2));
  float p3 = 1.f/(1.f+expf(-sc*l3));
  float s=0.f, s2=0.f;
  for (int c = 0; c < 512; ++c){
    float m = bs[c] + Mm[c][0]*p0 + Mm[c][1]*p1 + Mm[c][2]*p2 + Mm[c][3]*p3;
    s += m; s2 += m*m;
  }
  float mean = s*(1.f/512.f);
  float rs = rsqrtf(s2*(1.f/512.f) - mean*mean + 1e-5f);
  for (int c0 = 0; c0 < 512; c0 += 8){
    u16 ob[8];
    #pragma unroll
    for (int m = 0; m < 8; ++m){
      int c = c0 + m;
      float v = bs[c] + Mm[c][0]*p0 + Mm[c][1]*p1 + Mm[c][2]*p2 + Mm[c][3]*p3;
      ob[m] = f2bf((v - mean)*rs*gam[c] + bet[c]);
    }
    *(uint4*)&col[512 + c0] = *(uint4*)ob;
  }
}

// --------- MFMA GEMM (m97-style): Out = act(Wb @ XT^T + bias) --------------
// Wb [M][K] bf16 row-major; XT [C][1024] bf16 (column-major activations,
// row stride fixed 1024). 128x128 tile, BK=32, global_load_lds staging.
// grid (M/128, C/128): bi = blockIdx.x (fast, L2 panel reuse), bj = blockIdx.y
__global__ __launch_bounds__(256) void mfma_gemm_t(
    const u16* __restrict__ Wb, const float* __restrict__ bias,
    const u16* __restrict__ XT, int K, int M,
    float* __restrict__ OutF, u16* __restrict__ OutH, int do_gelu)
{
  __shared__ __align__(16) u16 As[128*32];
  __shared__ __align__(16) u16 Bs[128*32];
  const int tid = threadIdx.x;
  const int lane = tid & 63;
  const int wv = __builtin_amdgcn_readfirstlane(tid >> 6);
  const int bi = blockIdx.x, bj = blockIdx.y;
  const int roff = (wv >> 1) * 64;
  const int noff = (wv & 1) * 64;
  const int lm = lane & 15, quad = lane >> 4;

  f32x4 acc[4][4];
  #pragma unroll
  for (int i=0;i<4;++i){
    #pragma unroll
    for (int j=0;j<4;++j) acc[i][j] = (f32x4){0.f,0.f,0.f,0.f};
  }
  // staging map: thread -> row tid>>2 (0..63), chunk tid&3 (16B)
  const u16* aG = Wb + (size_t)(bi*128 + (tid>>2))*K + (tid&3)*8;
  const u16* bG = XT + (size_t)(bj*128 + (tid>>2))*1024 + (tid&3)*8;
  char* aL = (char*)As + wv*1024;     // lane dest auto +lane*16
  char* bL = (char*)Bs + wv*1024;

  for (int k0 = 0; k0 < K; k0 += 32){
    async16(aG + k0,            aL);
    async16(aG + 64*K + k0,     aL + 4096);
    async16(bG + k0,            bL);
    async16(bG + 64*1024 + k0,  bL + 4096);
    __syncthreads();               // drains vmcnt + barrier
    bfrag av[4], bv[4];
    #pragma unroll
    for (int i=0;i<4;++i)
      av[i] = *(const bfrag*)&As[(roff + 16*i + lm)*32 + quad*8];
    #pragma unroll
    for (int j=0;j<4;++j)
      bv[j] = *(const bfrag*)&Bs[(noff + 16*j + lm)*32 + quad*8];
    #pragma unroll
    for (int i=0;i<4;++i){
      #pragma unroll
      for (int j=0;j<4;++j)
        acc[i][j] = __builtin_amdgcn_mfma_f32_16x16x32_bf16(av[i], bv[j], acc[i][j], 0,0,0);
    }
    __syncthreads();
  }
  // transposed epilogue: Out[(col)*M + row]
  const int colBase = bj*128 + noff + lm;
  #pragma unroll
  for (int i=0;i<4;++i){
    int Rb = bi*128 + roff + 16*i + quad*4;
    #pragma unroll
    for (int r=0;r<4;++r){
      int R = Rb + r;
      float bb = bias[R];
      #pragma unroll
      for (int j=0;j<4;++j){
        float v = acc[i][j][r] + bb;
        if (do_gelu) v = gelu_f(v);
        size_t o = (size_t)(colBase + 16*j)*M + R;
        if (OutH) OutH[o] = f2bf(v);
        else      OutF[o] = v;
      }
    }
  }
}

// --------- MFMA GEMM 64-row (g1): Out[C][64] = Wg @ XT^T + b ---------------
// Wg [64][1024] bf16; XT [C][1024]; 64x256 tile, grid (C/256)
__global__ __launch_bounds__(256) void mfma_g64(
    const u16* __restrict__ Wg, const float* __restrict__ bias,
    const u16* __restrict__ XT, float* __restrict__ Out)
{
  __shared__ __align__(16) u16 As[64*32];
  __shared__ __align__(16) u16 Bs[256*32];
  const int tid = threadIdx.x;
  const int lane = tid & 63;
  const int wv = __builtin_amdgcn_readfirstlane(tid >> 6);
  const int bj = blockIdx.x;
  const int lm = lane & 15, quad = lane >> 4;

  f32x4 acc[4][4];
  #pragma unroll
  for (int i=0;i<4;++i){
    #pragma unroll
    for (int j=0;j<4;++j) acc[i][j] = (f32x4){0.f,0.f,0.f,0.f};
  }
  const u16* aG = Wg + (size_t)(tid>>2)*1024 + (tid&3)*8;
  const u16* bG = XT + (size_t)(bj*256 + (tid>>2))*1024 + (tid&3)*8;
  char* aL = (char*)As + wv*1024;
  char* bL = (char*)Bs + wv*1024;

  for (int k0 = 0; k0 < 1024; k0 += 32){
    async16(aG + k0, aL);
    #pragma unroll
    for (int s = 0; s < 4; ++s)
      async16(bG + (size_t)s*64*1024 + k0, bL + s*4096);
    __syncthreads();
    bfrag av[4], bv[4];
    #pragma unroll
    for (int i=0;i<4;++i)
      av[i] = *(const bfrag*)&As[(16*i + lm)*32 + quad*8];
    #pragma unroll
    for (int j=0;j<4;++j)
      bv[j] = *(const bfrag*)&Bs[(wv*64 + 16*j + lm)*32 + quad*8];
    #pragma unroll
    for (int i=0;i<4;++i){
      #pragma unroll
      for (int j=0;j<4;++j)
        acc[i][j] = __builtin_amdgcn_mfma_f32_16x16x32_bf16(av[i], bv[j], acc[i][j], 0,0,0);
    }
    __syncthreads();
  }
  const int colBase = bj*256 + wv*64 + lm;
  #pragma unroll
  for (int i=0;i<4;++i){
    int Rb = 16*i + quad*4;
    #pragma unroll
    for (int r=0;r<4;++r){
      int R = Rb + r;
      float bb = bias[R];
      #pragma unroll
      for (int j=0;j<4;++j)
        Out[(size_t)(colBase + 16*j)*64 + R] = acc[i][j][r] + bb;
    }
  }
}

// ---- LN over 512 channels, wave-per-column, coalesced; out bf16 into XYbT -
__global__ __launch_bounds__(256) void k_lnT(
    const float* __restrict__ t2T,
    const float* __restrict__ gamma, const float* __restrict__ beta,
    u16* __restrict__ XYbT)
{
  __shared__ float gam[512], bet[512];
  const int tid = threadIdx.x;
  for (int c = tid; c < 512; c += 256){ gam[c]=gamma[c]; bet[c]=beta[c]; }
  __syncthreads();
  const int lane = tid & 63, wv = tid >> 6;
  const int j = blockIdx.x*4 + wv;
  const float* p = t2T + (size_t)j*512 + lane*8;
  float4 v0 = *(const float4*)p;
  float4 v1 = *(const float4*)(p + 4);
  float vv[8] = {v0.x,v0.y,v0.z,v0.w,v1.x,v1.y,v1.z,v1.w};
  float s = 0.f, s2 = 0.f;
  #pragma unroll
  for (int m=0;m<8;++m){ s += vv[m]; s2 += vv[m]*vv[m]; }
  #pragma unroll
  for (int off = 32; off; off >>= 1){
    s  += __shfl_xor(s,  off, 64);
    s2 += __shfl_xor(s2, off, 64);
  }
  float mean = s*(1.f/512.f);
  float rs = rsqrtf(s2*(1.f/512.f) - mean*mean + 1e-5f);
  u16 ob[8];
  #pragma unroll
  for (int m=0;m<8;++m){
    int c = lane*8 + m;
    ob[m] = f2bf((vv[m]-mean)*rs*gam[c] + bet[c]);
  }
  *(uint4*)&XYbT[(size_t)j*1024 + 512 + lane*8] = *(uint4*)ob;
}

// ------- head: LN64+gelu -> 16 -> 4 -> 2, softmax ch0; G is [C][64] --------
__global__ __launch_bounds__(256) void k_head(
    const float* __restrict__ G,
    const float* __restrict__ gl1_g, const float* __restrict__ gl1_b,
    const float* __restrict__ g2_w, const float* __restrict__ g2_b,
    const float* __restrict__ gl2_g, const float* __restrict__ gl2_b,
    const float* __restrict__ g3_w, const float* __restrict__ g3_b,
    const float* __restrict__ gl3_g, const float* __restrict__ gl3_b,
    const float* __restrict__ g4_w, const float* __restrict__ g4_b, int has_g4b,
    float* __restrict__ Outp, int j0_global)
{
  __shared__ float L1g[64], L1b[64];
  __shared__ float W2[16][64], B2v[16], G2v[16], T2v[16];
  __shared__ float W3[4][16], B3v[4], G3v[4], T3v[4];
  __shared__ float W4d[4]; __shared__ float b4d;
  const int tid = threadIdx.x;
  if (tid < 64){ L1g[tid]=gl1_g[tid]; L1b[tid]=gl1_b[tid]; }
  for (int i = tid; i < 1024; i += 256) W2[i>>6][i&63] = g2_w[i];
  if (tid < 16){ B2v[tid]=g2_b[tid]; G2v[tid]=gl2_g[tid]; T2v[tid]=gl2_b[tid]; }
  if (tid < 64) W3[tid>>4][tid&15] = g3_w[tid];
  if (tid < 4){ B3v[tid]=g3_b[tid]; G3v[tid]=gl3_g[tid]; T3v[tid]=gl3_b[tid];
                W4d[tid] = g4_w[tid] - g4_w[4+tid]; }
  if (tid == 0) b4d = has_g4b ? (g4_b[0] - g4_b[1]) : 0.f;
  __syncthreads();
  const int jl = blockIdx.x*256 + tid;
  const float* gc = G + (size_t)jl*64;
  float a1[64]; float s=0.f;
  #pragma unroll
  for (int c0=0;c0<64;c0+=4){
    float4 v = *(const float4*)(gc + c0);
    a1[c0]=v.x; a1[c0+1]=v.y; a1[c0+2]=v.z; a1[c0+3]=v.w;
    s += v.x+v.y+v.z+v.w;
  }
  float m = s*(1.f/64.f); float s2=0.f;
  #pragma unroll
  for (int c=0;c<64;++c){ float d=a1[c]-m; s2+=d*d; }
  float rs = rsqrtf(s2*(1.f/64.f)+1e-5f);
  #pragma unroll
  for (int c=0;c<64;++c) a1[c] = gelu_f((a1[c]-m)*rs*L1g[c]+L1b[c]);

  float a2[16]; s=0.f;
  #pragma unroll
  for (int i=0;i<16;++i){
    float acc = B2v[i];
    #pragma unroll
    for (int o=0;o<64;++o) acc += W2[i][o]*a1[o];
    a2[i]=acc; s+=acc;
  }
  m = s*(1.f/16.f); s2=0.f;
  #pragma unroll
  for (int i=0;i<16;++i){ float d=a2[i]-m; s2+=d*d; }
  rs = rsqrtf(s2*(1.f/16.f)+1e-5f);
  float a2g[16];
  #pragma unroll
  for (int i=0;i<16;++i) a2g[i] = gelu_f((a2[i]-m)*rs*G2v[i]+T2v[i]);

  float a3[4]; s=0.f;
  #pragma unroll
  for (int i=0;i<4;++i){
    float acc=B3v[i];
    #pragma unroll
    for (int o=0;o<16;++o) acc += W3[i][o]*a2g[o];
    a3[i]=acc; s+=acc;
  }
  m = s*0.25f; s2=0.f;
  #pragma unroll
  for (int i=0;i<4;++i){ float d=a3[i]-m; s2+=d*d; }
  rs = rsqrtf(s2*0.25f+1e-5f);
  float z = b4d;
  #pragma unroll
  for (int i=0;i<4;++i) z += W4d[i]*gelu_f((a3[i]-m)*rs*G3v[i]+T3v[i]);
  Outp[j0_global + jl] = 1.f/(1.f+expf(-z));
}

extern "C" void kernel_launch(void* const* d_in, const int* in_sizes, int n_in,
                              void* d_out, int out_size, void* d_ws, size_t ws_size,
                              hipStream_t stream)
{
  const float* gtok  = (const float*)d_in[0];
  const float* x     = (const float*)d_in[1];
  const float* ws1_w = (const float*)d_in[2];
  const float* ws1_b = (const float*)d_in[3];
  const float* ws2_w = (const float*)d_in[4];
  const float* ws2_b = (const float*)d_in[5];
  const float* wc1_w = (const float*)d_in[6];
  const float* wc1_b = (const float*)d_in[7];
  const float* wc2_w = (const float*)d_in[8];
  const float* wc2_b = (const float*)d_in[9];
  const float* q_w   = (const float*)d_in[10];
  const float* q_b   = (const float*)d_in[11];
  const float* k_w   = (const float*)d_in[12];
  const float* v_w   = (const float*)d_in[14];
  const float* v_b   = (const float*)d_in[15];
  const float* merge_w = (const float*)d_in[16];
  const float* merge_b = (const float*)d_in[17];
  const float* m1_w  = (const float*)d_in[18];
  const float* m1_b  = (const float*)d_in[19];
  const float* m2_w  = (const float*)d_in[20];
  const float* m2_b  = (const float*)d_in[21];
  const float* n0_g  = (const float*)d_in[22];
  const float* n0_b  = (const float*)d_in[23];
  const float* n1_g  = (const float*)d_in[24];
  const float* n1_b  = (const float*)d_in[25];
  const float* g1_w  = (const float*)d_in[26];
  const float* g1_b  = (const float*)d_in[27];
  const float* gl1_g = (const float*)d_in[28];
  const float* gl1_b = (const float*)d_in[29];
  const float* g2_w  = (const float*)d_in[30];
  const float* g2_b  = (const float*)d_in[31];
  const float* gl2_g = (const float*)d_in[32];
  const float* gl2_b = (const float*)d_in[33];
  const float* g3_w  = (const float*)d_in[34];
  const float* g3_b  = (const float*)d_in[35];
  const float* gl3_g = (const float*)d_in[36];
  const float* gl3_b = (const float*)d_in[37];
  const float* g4_w  = (const float*)d_in[38];
  const float* g4_b  = (n_in > 39) ? (const float*)d_in[39] : nullptr;

  const int TOT = 65536;
  const size_t PRE_BYTES = (size_t)16 * PRE_STRIDE * 4;
  const size_t GT1_B = 65536, HID_B = 262144, GT2_B = 65536;
  const size_t DK_B = 32768, DV_B = 32768, V1L_B = 32768;
  const size_t WB1_B = (size_t)1024*1024*2;
  const size_t WB2_B = (size_t)512*1024*2;
  const size_t WG_B  = (size_t)64*1024*2;
  const size_t FIXED = PRE_BYTES + GT1_B + HID_B + GT2_B + DK_B + DV_B + V1L_B
                     + WB1_B + WB2_B + WG_B;
  // per-chunk: XYbT 2048C + T1bT 2048C + t2T 2048C + bufG 256C = 6400C bytes
  int C = 65536;
  while (C > 4096 && FIXED + (size_t)6400*C > ws_size) C >>= 1;
  const int nch = TOT / C;

  char* wsb = (char*)d_ws;
  size_t off = 0;
  float* PRE = (float*)(wsb + off); off += PRE_BYTES;
  float* GT1 = (float*)(wsb + off); off += GT1_B;
  float* HID = (float*)(wsb + off); off += HID_B;
  float* GT2 = (float*)(wsb + off); off += GT2_B;
  float* DK  = (float*)(wsb + off); off += DK_B;
  float* DV  = (float*)(wsb + off); off += DV_B;
  float* V1L = (float*)(wsb + off); off += V1L_B;
  u16* Wb1   = (u16*)(wsb + off);   off += WB1_B;
  u16* Wb2   = (u16*)(wsb + off);   off += WB2_B;
  u16* Wg    = (u16*)(wsb + off);   off += WG_B;
  u16* XYbT  = (u16*)(wsb + off);   off += (size_t)2048*C;  // [C][1024] bf16
  u16* T1bT  = (u16*)(wsb + off);   off += (size_t)2048*C;  // [C][1024] bf16
  float* t2T = (float*)(wsb + off); off += (size_t)2048*C;  // [C][512] fp32
  float* bufG= (float*)(wsb + off); off += (size_t)256*C;   // [C][64] fp32

  dim3 blk(256);
  hipLaunchKernelGGL(kcvt, dim3(512), blk, 0, stream, m1_w, Wb1, 1024*1024/8);
  hipLaunchKernelGGL(kcvt, dim3(256), blk, 0, stream, m2_w, Wb2, 512*1024/8);
  hipLaunchKernelGGL(kcvt_dup, dim3(256), blk, 0, stream, g1_w, Wg);
  hipLaunchKernelGGL(k0a_mlps, dim3(16,2), blk, 0, stream,
      gtok, ws1_w, ws1_b, ws2_w, ws2_b, GT1);
  hipLaunchKernelGGL(k0b_fc1, dim3(16,8), blk, 0, stream, GT1, wc1_w, wc1_b, HID);
  hipLaunchKernelGGL(k0c_fc2, dim3(16,2), blk, 0, stream, GT1, HID, wc2_w, wc2_b, GT2);
  hipLaunchKernelGGL(k0d_kv,  dim3(16,2), blk, 0, stream, GT2, k_w, v_w, v_b, DK, DV, V1L);
  hipLaunchKernelGGL(k0e_qpre, dim3(16,2), blk, 0, stream, DK, q_w, q_b, PRE);
  hipLaunchKernelGGL(k0f_mpre, dim3(16,2), blk, 0, stream, DV, V1L, merge_w, merge_b, PRE);

  for (int ch = 0; ch < nch; ++ch){
    const int j0 = ch * C;
    dim3 cols(C/256);
    // x->bf16 + attn + merge + LN(n0) in one pass over x -> XYbT
    hipLaunchKernelGGL(k1_fused, cols, blk, 0, stream,
        x, PRE, n0_g, n0_b, j0, XYbT);
    // t1 = gelu(m1 @ XY + b) -> T1bT (bf16, transposed)
    hipLaunchKernelGGL(mfma_gemm_t, dim3(8, C/128), blk, 0, stream,
        Wb1, m1_b, XYbT, 1024, 1024, (float*)nullptr, T1bT, 1);
    // t2 = m2 @ t1 + b -> t2T (fp32, transposed)
    hipLaunchKernelGGL(mfma_gemm_t, dim3(4, C/128), blk, 0, stream,
        Wb2, m2_b, T1bT, 1024, 512, t2T, (u16*)nullptr, 0);
    // LN(t2; n1) -> bf16, overwrite y-half of XYbT (x-half stays = x bf16)
    hipLaunchKernelGGL(k_lnT, dim3(C/4), blk, 0, stream, t2T, n1_g, n1_b, XYbT);
    // g1raw = [g1_w|g1_w] @ [x; LN(t2)] + b  (residual folded into GEMM)
    hipLaunchKernelGGL(mfma_g64, dim3(C/256), blk, 0, stream, Wg, g1_b, XYbT, bufG);
    // head
    hipLaunchKernelGGL(k_head, cols, blk, 0, stream,
        bufG, gl1_g, gl1_b, g2_w, g2_b, gl2_g, gl2_b,
        g3_w, g3_b, gl3_g, gl3_b,
        g4_w, g4_b ? g4_b : g4_w, g4_b ? 1 : 0, (float*)d_out, j0);
  }
}